// Round 3
// baseline (1558.678 us; speedup 1.0000x reference)
//
#include <hip/hip_runtime.h>
#include <math.h>

#define D 128
#define NNODES 8192
#define NEDGES 16384
#define NSTEMS 4096
#define NGRAPHS 256
#define NSTEPS 12
#define OPS 105
#define SLOPE 0.01f
#define SLOC_CAP 512
#define MT 32          // nodes per mega block
#define NB (NNODES / MT)   // 256 blocks
#define LDA 136        // padded halfs per LDS row

typedef _Float16 half_t;
typedef __attribute__((ext_vector_type(8))) _Float16 f16x8;
typedef __attribute__((ext_vector_type(4))) float f32x4;

__device__ __forceinline__ float leaky(float x) { return x > 0.f ? x : SLOPE * x; }
__device__ __forceinline__ float fast_sigmoid(float x) {
    return __builtin_amdgcn_rcpf(1.f + __expf(-x));
}
__device__ __forceinline__ float fast_tanh(float x) {
    float e = __expf(2.f * x);
    return 1.f - 2.f * __builtin_amdgcn_rcpf(e + 1.f);
}

// ---------------- setup kernels ----------------

__global__ void k_zero(float* p, int n) {
    int i = blockIdx.x * 256 + threadIdx.x;
    if (i < n) p[i] = 0.f;
}

__global__ void k_deg(const int* __restrict__ eidx, int* __restrict__ deg) {
    int e = blockIdx.x * 256 + threadIdx.x;
    if (e < NEDGES) atomicAdd(&deg[eidx[NEDGES + e]], 1);
}

__global__ void k_scan(const int* __restrict__ deg, int* __restrict__ row_start,
                       float* __restrict__ inv_deg) {
    __shared__ int sums[256];
    int t = threadIdx.x;
    int base = t * 32;
    int s = 0;
    for (int k = 0; k < 32; ++k) s += deg[base + k];
    sums[t] = s;
    __syncthreads();
    for (int off = 1; off < 256; off <<= 1) {
        int v = sums[t];
        int u = (t >= off) ? sums[t - off] : 0;
        __syncthreads();
        sums[t] = v + u;
        __syncthreads();
    }
    int run = sums[t] - s;
    for (int k = 0; k < 32; ++k) {
        int d = deg[base + k];
        row_start[base + k] = run;
        run += d;
        inv_deg[base + k] = (d > 0) ? (1.0f / (float)d) : 0.0f;
    }
    if (t == 255) row_start[NNODES] = run;
}

__global__ void k_scatter(const int* __restrict__ eidx, const int* __restrict__ row_start,
                          int* __restrict__ fill, int* __restrict__ edge_list) {
    int e = blockIdx.x * 256 + threadIdx.x;
    if (e < NEDGES) {
        int d = eidx[NEDGES + e];
        int pos = row_start[d] + atomicAdd(&fill[d], 1);
        edge_list[pos] = e;
    }
}

__device__ __forceinline__ void tr(const float* __restrict__ src, float* __restrict__ dst,
                                   int rows, int cols, int idx) {
    if (idx < rows * cols) {
        int r = idx / cols;
        int c = idx - r * cols;
        dst[c * rows + r] = src[idx];
    }
}

__global__ void k_transpose_all(
    const float* bw1, const float* bw2,
    const float* sw1, const float* sw2, const float* sw3, const float* gw1,
    float* w1T, float* w2T, float* s1T, float* s2T, float* s3T, float* g1T) {
    int idx = blockIdx.x * 256 + threadIdx.x;
    switch (blockIdx.y) {
        case 0: tr(bw1, w1T, 128, 128, idx); break;
        case 1: tr(bw2, w2T, 128, 128, idx); break;
        case 2: tr(sw1, s1T, 128, 256, idx); break;
        case 3: tr(sw2, s2T, 128, 128, idx); break;
        case 4: tr(sw3, s3T, 105, 128, idx); break;
        case 5: tr(gw1, g1T, 128, 128, idx); break;
    }
}

// Pack weights into MFMA B-fragment order, fp16.
// B-frag 16x16x32: lane L supplies B[k = kt*32 + (L>>4)*8 + j][n = nt*16 + (L&15)], j=0..7.
__global__ void k_pack(const float* __restrict__ root, const float* __restrict__ wih,
                       const float* __restrict__ whh,
                       half_t* __restrict__ rootP, half_t* __restrict__ WihP,
                       half_t* __restrict__ WhhP) {
    int idx = blockIdx.x * 256 + threadIdx.x;
    int which = blockIdx.y;
    int NT = (which == 0) ? 8 : 24;
    if (idx >= NT * 4 * 512) return;
    int j = idx & 7;
    int L = (idx >> 3) & 63;
    int t = idx >> 9;
    int kt = t & 3, nt = t >> 2;
    int k = kt * 32 + (L >> 4) * 8 + j;
    int n = nt * 16 + (L & 15);
    if (which == 0) rootP[idx] = (half_t)root[k * D + n];
    else if (which == 1) WihP[idx] = (half_t)wih[n * D + k];
    else WhhP[idx] = (half_t)whh[n * D + k];
}

// ---------------- node init: out = act(emb@W1.T+b1)@W2.T+b2 (fp32) ----------------
__global__ __launch_bounds__(256) void k_init(
    const int* __restrict__ x, const float* __restrict__ embBlock,
    const float* __restrict__ w1T, const float* __restrict__ b1,
    const float* __restrict__ w2T, const float* __restrict__ b2,
    half_t* __restrict__ outH, float* __restrict__ hF) {
    __shared__ float es[16][D];
    __shared__ float ts[16][D];
    int tid = threadIdx.x;
    int j = tid & 127;
    int sub = tid >> 7;
    int n0 = blockIdx.x * 16;

    for (int ss = 0; ss < 8; ++ss) {
        int nn = sub * 8 + ss;
        es[nn][j] = embBlock[x[n0 + nn] * D + j];
    }
    __syncthreads();

    float acc[8];
    float bb = b1[j];
#pragma unroll
    for (int ss = 0; ss < 8; ++ss) acc[ss] = bb;
    for (int i = 0; i < D; i += 4) {
        float w0 = w1T[(i + 0) * D + j];
        float w1 = w1T[(i + 1) * D + j];
        float w2 = w1T[(i + 2) * D + j];
        float w3 = w1T[(i + 3) * D + j];
#pragma unroll
        for (int ss = 0; ss < 8; ++ss) {
            float4 v = *(const float4*)&es[sub * 8 + ss][i];
            acc[ss] += v.x * w0 + v.y * w1 + v.z * w2 + v.w * w3;
        }
    }
#pragma unroll
    for (int ss = 0; ss < 8; ++ss) ts[sub * 8 + ss][j] = leaky(acc[ss]);
    __syncthreads();

    bb = b2[j];
#pragma unroll
    for (int ss = 0; ss < 8; ++ss) acc[ss] = bb;
    for (int i = 0; i < D; i += 4) {
        float w0 = w2T[(i + 0) * D + j];
        float w1 = w2T[(i + 1) * D + j];
        float w2v = w2T[(i + 2) * D + j];
        float w3 = w2T[(i + 3) * D + j];
#pragma unroll
        for (int ss = 0; ss < 8; ++ss) {
            float4 v = *(const float4*)&ts[sub * 8 + ss][i];
            acc[ss] += v.x * w0 + v.y * w1 + v.z * w2v + v.w * w3;
        }
    }
#pragma unroll
    for (int ss = 0; ss < 8; ++ss) {
        int n = n0 + sub * 8 + ss;
        hF[n * D + j] = acc[ss];
        outH[n * D + j] = (half_t)acc[ss];
    }
}

// ---------------- persistent 12-step conv+GRU mega-kernel ----------------
// 256 blocks x 512 threads; block owns 32 nodes for all 12 steps.
// h state: fp32 in registers (C-fragment layout) + fp16 LDS tile (A-operand).
// Grid barrier between steps (monotone counter, agent-scope fences).
__global__ __launch_bounds__(512) void k_mega(
    half_t* __restrict__ out0, half_t* __restrict__ out1, float* __restrict__ hF,
    const float* __restrict__ bond,
    const half_t* __restrict__ rootP, const half_t* __restrict__ WihP,
    const half_t* __restrict__ WhhP,
    const float* __restrict__ cbias, const float* __restrict__ bih,
    const float* __restrict__ bhh,
    const int* __restrict__ eidx, const int* __restrict__ eattr,
    const int* __restrict__ row_start, const int* __restrict__ edge_list,
    const float* __restrict__ inv_deg, int* __restrict__ ctr) {
    __shared__ __align__(16) half_t As[MT * LDA];    // h tile, fp16 (A-operand)
    __shared__ __align__(16) half_t Am[MT * LDA];    // m tile, fp16
    __shared__ float sloc[SLOC_CAP];

    const int tid = threadIdx.x;
    const int w = tid >> 6;
    const int lane = tid & 63;
    const int quad = lane >> 4;
    const int l16 = lane & 15;
    const int n0 = blockIdx.x * MT;
    const int c = w * 16 + l16;          // this lane's gate column

    // --- seed h fragments from init's hF (fp32), fill As ---
    float h[2][4];
#pragma unroll
    for (int mt = 0; mt < 2; ++mt)
#pragma unroll
        for (int r = 0; r < 4; ++r) {
            int rowl = mt * 16 + quad * 4 + r;
            float v = hF[(size_t)(n0 + rowl) * D + c];
            h[mt][r] = v;
            As[rowl * LDA + c] = (half_t)v;
        }
    const int p0 = row_start[n0];
    const int p1 = row_start[n0 + MT];
    const float cb = cbias[c];
    const float bi0 = bih[c], bi1 = bih[D + c], bi2 = bih[2 * D + c];
    const float bh0 = bhh[c], bh1 = bhh[D + c], bh2 = bhh[2 * D + c];
    const float idg[2][4] = {
        {inv_deg[n0 + quad * 4 + 0], inv_deg[n0 + quad * 4 + 1],
         inv_deg[n0 + quad * 4 + 2], inv_deg[n0 + quad * 4 + 3]},
        {inv_deg[n0 + 16 + quad * 4 + 0], inv_deg[n0 + 16 + quad * 4 + 1],
         inv_deg[n0 + 16 + quad * 4 + 2], inv_deg[n0 + 16 + quad * 4 + 3]}};
    __syncthreads();

    for (int s = 0; s < NSTEPS; ++s) {
        const half_t* __restrict__ cur = (s & 1) ? out1 : out0;
        half_t* __restrict__ nxt = (s & 1) ? out0 : out1;

        // --- edge dots: s_e = dot(out[src], bond[ea0]) ---
        for (int p = p0 + w; p < p1; p += 8) {
            int e = edge_list[p];
            int src = eidx[e];
            int a0 = eattr[2 * e];
            float v = (float)cur[(size_t)src * D + lane] * bond[a0 * D + lane] +
                      (float)cur[(size_t)src * D + 64 + lane] * bond[a0 * D + 64 + lane];
#pragma unroll
            for (int off = 32; off >= 1; off >>= 1) v += __shfl_xor(v, off, 64);
            int rel = p - p0;
            if (lane == 0 && rel < SLOC_CAP) sloc[rel] = v;
        }

        // --- conv GEMM: h_tile @ root (wave's 16 cols) ---
        f32x4 convAcc[2] = {f32x4{0.f, 0.f, 0.f, 0.f}, f32x4{0.f, 0.f, 0.f, 0.f}};
#pragma unroll
        for (int kt = 0; kt < 4; ++kt) {
            f16x8 b = *(const f16x8*)(rootP + (size_t)((w * 4 + kt) * 64 + lane) * 8);
            f16x8 a0 = *(const f16x8*)&As[(0 * 16 + l16) * LDA + kt * 32 + quad * 8];
            f16x8 a1 = *(const f16x8*)&As[(1 * 16 + l16) * LDA + kt * 32 + quad * 8];
            convAcc[0] = __builtin_amdgcn_mfma_f32_16x16x32_f16(a0, b, convAcc[0], 0, 0, 0);
            convAcc[1] = __builtin_amdgcn_mfma_f32_16x16x32_f16(a1, b, convAcc[1], 0, 0, 0);
        }
        // --- gh GEMM: h_tile @ Whh^T (3 gates) ---
        f32x4 ghAcc[2][3];
#pragma unroll
        for (int mt = 0; mt < 2; ++mt)
#pragma unroll
            for (int g = 0; g < 3; ++g) ghAcc[mt][g] = f32x4{0.f, 0.f, 0.f, 0.f};
#pragma unroll
        for (int kt = 0; kt < 4; ++kt) {
            f16x8 a0 = *(const f16x8*)&As[(0 * 16 + l16) * LDA + kt * 32 + quad * 8];
            f16x8 a1 = *(const f16x8*)&As[(1 * 16 + l16) * LDA + kt * 32 + quad * 8];
#pragma unroll
            for (int g = 0; g < 3; ++g) {
                f16x8 b = *(const f16x8*)(WhhP + (size_t)(((g * 8 + w) * 4 + kt) * 64 + lane) * 8);
                ghAcc[0][g] = __builtin_amdgcn_mfma_f32_16x16x32_f16(a0, b, ghAcc[0][g], 0, 0, 0);
                ghAcc[1][g] = __builtin_amdgcn_mfma_f32_16x16x32_f16(a1, b, ghAcc[1][g], 0, 0, 0);
            }
        }
        __syncthreads();   // sloc ready; As reads done

        // --- aggregation at fragment positions, m = leaky(conv + cb + agg/deg) ---
#pragma unroll
        for (int mt = 0; mt < 2; ++mt) {
#pragma unroll
            for (int r = 0; r < 4; ++r) {
                int rowl = mt * 16 + quad * 4 + r;
                int node = n0 + rowl;
                float a = 0.f;
                int q0 = row_start[node], q1 = row_start[node + 1];
                for (int p = q0; p < q1; ++p) {
                    int e = edge_list[p];
                    int a1i = eattr[2 * e + 1];
                    int rel = p - p0;
                    float sv;
                    if (rel < SLOC_CAP) sv = sloc[rel];
                    else {
                        int s2 = eidx[e];
                        int a0i = eattr[2 * e];
                        sv = 0.f;
                        for (int i = 0; i < D; ++i)
                            sv += (float)cur[(size_t)s2 * D + i] * bond[a0i * D + i];
                    }
                    a += sv * bond[a1i * D + c];
                }
                float m = convAcc[mt][r] + cb + a * idg[mt][r];
                Am[rowl * LDA + c] = (half_t)leaky(m);
            }
        }
        __syncthreads();   // Am ready

        // --- gi GEMM: m_tile @ Wih^T ---
        f32x4 giAcc[2][3];
#pragma unroll
        for (int mt = 0; mt < 2; ++mt)
#pragma unroll
            for (int g = 0; g < 3; ++g) giAcc[mt][g] = f32x4{0.f, 0.f, 0.f, 0.f};
#pragma unroll
        for (int kt = 0; kt < 4; ++kt) {
            f16x8 a0 = *(const f16x8*)&Am[(0 * 16 + l16) * LDA + kt * 32 + quad * 8];
            f16x8 a1 = *(const f16x8*)&Am[(1 * 16 + l16) * LDA + kt * 32 + quad * 8];
#pragma unroll
            for (int g = 0; g < 3; ++g) {
                f16x8 b = *(const f16x8*)(WihP + (size_t)(((g * 8 + w) * 4 + kt) * 64 + lane) * 8);
                giAcc[0][g] = __builtin_amdgcn_mfma_f32_16x16x32_f16(a0, b, giAcc[0][g], 0, 0, 0);
                giAcc[1][g] = __builtin_amdgcn_mfma_f32_16x16x32_f16(a1, b, giAcc[1][g], 0, 0, 0);
            }
        }

        // --- GRU combine; update h regs, As (for next step), global out ---
        bool last = (s == NSTEPS - 1);
#pragma unroll
        for (int mt = 0; mt < 2; ++mt) {
#pragma unroll
            for (int r = 0; r < 4; ++r) {
                int rowl = mt * 16 + quad * 4 + r;
                float rg = fast_sigmoid(giAcc[mt][0][r] + bi0 + ghAcc[mt][0][r] + bh0);
                float z = fast_sigmoid(giAcc[mt][1][r] + bi1 + ghAcc[mt][1][r] + bh1);
                float nn = fast_tanh(giAcc[mt][2][r] + bi2 + rg * (ghAcc[mt][2][r] + bh2));
                float hnew = (1.f - z) * nn + z * h[mt][r];
                h[mt][r] = hnew;
                As[rowl * LDA + c] = (half_t)hnew;
                if (!last) nxt[(size_t)(n0 + rowl) * D + c] = (half_t)hnew;
            }
        }

        if (!last) {
            // grid barrier: release writes, arrive, spin, acquire
            __threadfence();
            __syncthreads();
            if (tid == 0) {
                atomicAdd(ctr, 1);
                int target = NB * (s + 1);
                while (__hip_atomic_load(ctr, __ATOMIC_RELAXED, __HIP_MEMORY_SCOPE_AGENT) < target)
                    __builtin_amdgcn_s_sleep(2);
            }
            __syncthreads();
            __threadfence();
        }
    }

    // --- write final h (fp32) for the heads ---
#pragma unroll
    for (int mt = 0; mt < 2; ++mt)
#pragma unroll
        for (int r = 0; r < 4; ++r) {
            int rowl = mt * 16 + quad * 4 + r;
            hF[(size_t)(n0 + rowl) * D + c] = h[mt][r];
        }
}

// ---------------- stem head (fp32) ----------------
__global__ __launch_bounds__(256) void k_stem(
    const float* __restrict__ out0, const int* __restrict__ sni, const int* __restrict__ stypes,
    const float* __restrict__ embStem,
    const float* __restrict__ w1T, const float* __restrict__ b1,
    const float* __restrict__ w2T, const float* __restrict__ b2,
    const float* __restrict__ w3T, const float* __restrict__ b3,
    float* __restrict__ dout) {
    __shared__ float cat[16][2 * D];
    __shared__ float s1[16][D];
    __shared__ float s2[16][D];
    int tid = threadIdx.x;
    int j = tid & 127;
    int sub = tid >> 7;
    int s0 = blockIdx.x * 16;

    for (int ss = 0; ss < 16; ++ss) {
        int s = s0 + ss;
        if (tid < 128) cat[ss][tid] = out0[sni[s] * D + tid];
        else cat[ss][tid] = embStem[stypes[s] * D + (tid - 128)];
    }
    __syncthreads();

    float acc[8];
    {
        float bb = b1[j];
#pragma unroll
        for (int ss = 0; ss < 8; ++ss) acc[ss] = bb;
        for (int i = 0; i < 2 * D; i += 4) {
            float w0 = w1T[(i + 0) * D + j];
            float w1 = w1T[(i + 1) * D + j];
            float w2 = w1T[(i + 2) * D + j];
            float w3 = w1T[(i + 3) * D + j];
#pragma unroll
            for (int ss = 0; ss < 8; ++ss) {
                float4 v = *(const float4*)&cat[sub * 8 + ss][i];
                acc[ss] += v.x * w0 + v.y * w1 + v.z * w2 + v.w * w3;
            }
        }
#pragma unroll
        for (int ss = 0; ss < 8; ++ss) s1[sub * 8 + ss][j] = leaky(acc[ss]);
    }
    __syncthreads();
    {
        float bb = b2[j];
#pragma unroll
        for (int ss = 0; ss < 8; ++ss) acc[ss] = bb;
        for (int i = 0; i < D; i += 4) {
            float w0 = w2T[(i + 0) * D + j];
            float w1 = w2T[(i + 1) * D + j];
            float w2 = w2T[(i + 2) * D + j];
            float w3 = w2T[(i + 3) * D + j];
#pragma unroll
            for (int ss = 0; ss < 8; ++ss) {
                float4 v = *(const float4*)&s1[sub * 8 + ss][i];
                acc[ss] += v.x * w0 + v.y * w1 + v.z * w2 + v.w * w3;
            }
        }
#pragma unroll
        for (int ss = 0; ss < 8; ++ss) s2[sub * 8 + ss][j] = leaky(acc[ss]);
    }
    __syncthreads();
    if (j < OPS) {
        float bb = b3[j];
#pragma unroll
        for (int ss = 0; ss < 8; ++ss) acc[ss] = bb;
        for (int i = 0; i < D; i += 4) {
            float w0 = w3T[(i + 0) * OPS + j];
            float w1 = w3T[(i + 1) * OPS + j];
            float w2 = w3T[(i + 2) * OPS + j];
            float w3 = w3T[(i + 3) * OPS + j];
#pragma unroll
            for (int ss = 0; ss < 8; ++ss) {
                float4 v = *(const float4*)&s2[sub * 8 + ss][i];
                acc[ss] += v.x * w0 + v.y * w1 + v.z * w2 + v.w * w3;
            }
        }
#pragma unroll
        for (int ss = 0; ss < 8; ++ss) {
            int s = s0 + sub * 8 + ss;
            dout[s * OPS + j] = acc[ss];
        }
    }
}

// ---------------- global mean pool + stop head (sorted segments, no atomics) ----------------
__device__ __forceinline__ int lower_bound_dev(const int* a, int n, int v) {
    int lo = 0, hi = n;
    while (lo < hi) {
        int m = (lo + hi) >> 1;
        if (a[m] < v) lo = m + 1;
        else hi = m;
    }
    return lo;
}

__global__ __launch_bounds__(128) void k_gpred(
    const float* __restrict__ hF, const int* __restrict__ batch,
    const float* __restrict__ g1T, const float* __restrict__ b1,
    const float* __restrict__ w2, const float* __restrict__ b2,
    float* __restrict__ dout) {
    __shared__ float mean_s[D];
    __shared__ float red[D];
    int g = blockIdx.x;
    int j = threadIdx.x;
    int lo = lower_bound_dev(batch, NNODES, g);
    int hi = lower_bound_dev(batch, NNODES, g + 1);
    float sum = 0.f;
    for (int n = lo; n < hi; ++n) sum += hF[(size_t)n * D + j];
    float denom = (hi > lo) ? (float)(hi - lo) : 1.0f;
    mean_s[j] = sum / denom;
    __syncthreads();
    float a = b1[j];
    for (int i = 0; i < D; ++i) a += mean_s[i] * g1T[i * D + j];
    a = leaky(a);
    red[j] = a * w2[j];
    __syncthreads();
    for (int off = 64; off > 0; off >>= 1) {
        if (j < off) red[j] += red[j + off];
        __syncthreads();
    }
    if (j == 0) dout[NSTEMS * OPS + g] = red[0] + b2[0];
}

// ---------------- launch ----------------
extern "C" void kernel_launch(void* const* d_in, const int* in_sizes, int n_in,
                              void* d_out, int out_size, void* d_ws, size_t ws_size,
                              hipStream_t stream) {
    const int* x = (const int*)d_in[0];
    const int* stypes = (const int*)d_in[1];
    const int* eattr = (const int*)d_in[2];
    const int* eidx = (const int*)d_in[3];
    const int* sni = (const int*)d_in[4];
    const int* batch = (const int*)d_in[5];
    const float* embBlock = (const float*)d_in[6];
    const float* embStem = (const float*)d_in[7];
    const float* embBond = (const float*)d_in[8];
    const float* b2e_w1 = (const float*)d_in[9];
    const float* b2e_b1 = (const float*)d_in[10];
    const float* b2e_w2 = (const float*)d_in[11];
    const float* b2e_b2 = (const float*)d_in[12];
    const float* conv_root = (const float*)d_in[13];
    const float* conv_bias = (const float*)d_in[14];
    const float* gru_w_ih = (const float*)d_in[15];
    const float* gru_w_hh = (const float*)d_in[16];
    const float* gru_b_ih = (const float*)d_in[17];
    const float* gru_b_hh = (const float*)d_in[18];
    const float* s2p_w1 = (const float*)d_in[19];
    const float* s2p_b1 = (const float*)d_in[20];
    const float* s2p_w2 = (const float*)d_in[21];
    const float* s2p_b2 = (const float*)d_in[22];
    const float* s2p_w3 = (const float*)d_in[23];
    const float* s2p_b3 = (const float*)d_in[24];
    const float* g2p_w1 = (const float*)d_in[25];
    const float* g2p_b1 = (const float*)d_in[26];
    const float* g2p_w2 = (const float*)d_in[27];
    const float* g2p_b2 = (const float*)d_in[28];
    float* out_f = (float*)d_out;

    float* W = (float*)d_ws;
    size_t off = 0;
    auto alloc = [&](size_t words) {
        size_t o = off;
        off += (words + 3) & ~(size_t)3;
        return o;
    };
    half_t* outHA = (half_t*)(W + alloc(NNODES * D / 2));
    half_t* outHB = (half_t*)(W + alloc(NNODES * D / 2));
    float* hF = W + alloc(NNODES * D);
    half_t* rootP = (half_t*)(W + alloc(8 * 4 * 512 / 2));
    half_t* WihP = (half_t*)(W + alloc(24 * 4 * 512 / 2));
    half_t* WhhP = (half_t*)(W + alloc(24 * 4 * 512 / 2));
    float* w1T = W + alloc(128 * 128);
    float* w2T = W + alloc(128 * 128);
    float* s1T = W + alloc(256 * 128);
    float* s2T = W + alloc(128 * 128);
    float* s3T = W + alloc(128 * 105);
    float* g1T = W + alloc(128 * 128);
    int* row_start = (int*)(W + alloc(NNODES + 1));
    int* edge_list = (int*)(W + alloc(NEDGES));
    float* inv_deg = W + alloc(NNODES);
    const int zwords = NNODES + NNODES + 16;   // deg + fill + barrier ctr
    float* zbase = W + alloc(zwords);
    int* deg = (int*)zbase;
    int* fill = deg + NNODES;
    int* ctr = fill + NNODES;

    k_zero<<<(zwords + 255) / 256, 256, 0, stream>>>(zbase, zwords);
    k_transpose_all<<<dim3(128, 6), 256, 0, stream>>>(
        b2e_w1, b2e_w2, s2p_w1, s2p_w2, s2p_w3, g2p_w1,
        w1T, w2T, s1T, s2T, s3T, g1T);
    k_pack<<<dim3(192, 3), 256, 0, stream>>>(conv_root, gru_w_ih, gru_w_hh,
                                             rootP, WihP, WhhP);
    k_deg<<<(NEDGES + 255) / 256, 256, 0, stream>>>(eidx, deg);
    k_scan<<<1, 256, 0, stream>>>(deg, row_start, inv_deg);
    k_scatter<<<(NEDGES + 255) / 256, 256, 0, stream>>>(eidx, row_start, fill, edge_list);
    k_init<<<NNODES / 16, 256, 0, stream>>>(x, embBlock, w1T, b2e_b1, w2T, b2e_b2, outHA, hF);

    k_mega<<<NB, 512, 0, stream>>>(outHA, outHB, hF, embBond, rootP, WihP, WhhP,
                                   conv_bias, gru_b_ih, gru_b_hh,
                                   eidx, eattr, row_start, edge_list, inv_deg, ctr);

    k_stem<<<NSTEMS / 16, 256, 0, stream>>>(hF, sni, stypes, embStem,
                                            s1T, s2p_b1, s2T, s2p_b2, s3T, s2p_b3, out_f);
    k_gpred<<<NGRAPHS, 128, 0, stream>>>(hF, batch, g1T, g2p_b1, g2p_w2, g2p_b2, out_f);
}

// Round 4
// 423.232 us; speedup vs baseline: 3.6828x; 3.6828x over previous
//
#include <hip/hip_runtime.h>
#include <math.h>

#define D 128
#define NNODES 8192
#define NEDGES 16384
#define NSTEMS 4096
#define NGRAPHS 256
#define NSTEPS 12
#define OPS 105
#define SLOPE 0.01f
#define MT 16              // nodes per step-block
#define NB (NNODES / MT)   // 512 blocks -> 2 blocks/CU
#define LDA 136            // padded halfs per LDS row

typedef _Float16 half_t;
typedef __attribute__((ext_vector_type(8))) _Float16 f16x8;
typedef __attribute__((ext_vector_type(4))) _Float16 f16x4;
typedef __attribute__((ext_vector_type(4))) float f32x4;

__device__ __forceinline__ float leaky(float x) { return x > 0.f ? x : SLOPE * x; }
__device__ __forceinline__ float fast_sigmoid(float x) {
    return __builtin_amdgcn_rcpf(1.f + __expf(-x));
}
__device__ __forceinline__ float fast_tanh(float x) {
    float e = __expf(2.f * x);
    return 1.f - 2.f * __builtin_amdgcn_rcpf(e + 1.f);
}

// ---------------- setup kernels ----------------

__global__ void k_zero(float* p, int n) {
    int i = blockIdx.x * 256 + threadIdx.x;
    if (i < n) p[i] = 0.f;
}

__global__ void k_deg(const int* __restrict__ eidx, int* __restrict__ deg) {
    int e = blockIdx.x * 256 + threadIdx.x;
    if (e < NEDGES) atomicAdd(&deg[eidx[NEDGES + e]], 1);
}

__global__ void k_scan(const int* __restrict__ deg, int* __restrict__ row_start,
                       float* __restrict__ inv_deg) {
    __shared__ int sums[256];
    int t = threadIdx.x;
    int base = t * 32;
    int s = 0;
    for (int k = 0; k < 32; ++k) s += deg[base + k];
    sums[t] = s;
    __syncthreads();
    for (int off = 1; off < 256; off <<= 1) {
        int v = sums[t];
        int u = (t >= off) ? sums[t - off] : 0;
        __syncthreads();
        sums[t] = v + u;
        __syncthreads();
    }
    int run = sums[t] - s;
    for (int k = 0; k < 32; ++k) {
        int d = deg[base + k];
        row_start[base + k] = run;
        run += d;
        inv_deg[base + k] = (d > 0) ? (1.0f / (float)d) : 0.0f;
    }
    if (t == 255) row_start[NNODES] = run;
}

__global__ void k_scatter(const int* __restrict__ eidx, const int* __restrict__ row_start,
                          int* __restrict__ fill, int* __restrict__ edge_list) {
    int e = blockIdx.x * 256 + threadIdx.x;
    if (e < NEDGES) {
        int d = eidx[NEDGES + e];
        int pos = row_start[d] + atomicAdd(&fill[d], 1);
        edge_list[pos] = e;
    }
}

__device__ __forceinline__ void tr(const float* __restrict__ src, float* __restrict__ dst,
                                   int rows, int cols, int idx) {
    if (idx < rows * cols) {
        int r = idx / cols;
        int c = idx - r * cols;
        dst[c * rows + r] = src[idx];
    }
}

__global__ void k_transpose_all(
    const float* bw1, const float* bw2,
    const float* sw1, const float* sw2, const float* sw3, const float* gw1,
    float* w1T, float* w2T, float* s1T, float* s2T, float* s3T, float* g1T) {
    int idx = blockIdx.x * 256 + threadIdx.x;
    switch (blockIdx.y) {
        case 0: tr(bw1, w1T, 128, 128, idx); break;
        case 1: tr(bw2, w2T, 128, 128, idx); break;
        case 2: tr(sw1, s1T, 128, 256, idx); break;
        case 3: tr(sw2, s2T, 128, 128, idx); break;
        case 4: tr(sw3, s3T, 105, 128, idx); break;
        case 5: tr(gw1, g1T, 128, 128, idx); break;
    }
}

// Pack weights into MFMA B-fragment order, fp16.
// B-frag 16x16x32: lane L supplies B[k = kt*32 + (L>>4)*8 + j][n = nt*16 + (L&15)], j=0..7.
__global__ void k_pack(const float* __restrict__ root, const float* __restrict__ wih,
                       const float* __restrict__ whh, const float* __restrict__ bond,
                       half_t* __restrict__ rootP, half_t* __restrict__ WihP,
                       half_t* __restrict__ WhhP, half_t* __restrict__ bondTP) {
    int idx = blockIdx.x * 256 + threadIdx.x;
    int which = blockIdx.y;
    int NT = (which == 0) ? 8 : (which == 3) ? 2 : 24;
    if (idx >= NT * 4 * 512) return;
    int j = idx & 7;
    int L = (idx >> 3) & 63;
    int t = idx >> 9;
    int kt = t & 3, nt = t >> 2;
    int k = kt * 32 + (L >> 4) * 8 + j;
    int n = nt * 16 + (L & 15);
    if (which == 0) rootP[idx] = (half_t)root[k * D + n];        // B[k][n] = root[k][n]
    else if (which == 1) WihP[idx] = (half_t)wih[n * D + k];     // B[k][n] = wih[n][k]
    else if (which == 2) WhhP[idx] = (half_t)whh[n * D + k];
    else bondTP[idx] = (half_t)bond[n * D + k];                  // P = h @ bond^T : B[k][n] = bond[n][k]
}

// ---------------- node init: h0 = act(emb@W1.T+b1)@W2.T+b2 (fp32) ----------------
__global__ __launch_bounds__(256) void k_init(
    const int* __restrict__ x, const float* __restrict__ embBlock,
    const float* __restrict__ w1T, const float* __restrict__ b1,
    const float* __restrict__ w2T, const float* __restrict__ b2,
    float* __restrict__ hF) {
    __shared__ float es[16][D];
    __shared__ float ts[16][D];
    int tid = threadIdx.x;
    int j = tid & 127;
    int sub = tid >> 7;
    int n0 = blockIdx.x * 16;

    for (int ss = 0; ss < 8; ++ss) {
        int nn = sub * 8 + ss;
        es[nn][j] = embBlock[x[n0 + nn] * D + j];
    }
    __syncthreads();

    float acc[8];
    float bb = b1[j];
#pragma unroll
    for (int ss = 0; ss < 8; ++ss) acc[ss] = bb;
    for (int i = 0; i < D; i += 4) {
        float w0 = w1T[(i + 0) * D + j];
        float w1 = w1T[(i + 1) * D + j];
        float w2 = w1T[(i + 2) * D + j];
        float w3 = w1T[(i + 3) * D + j];
#pragma unroll
        for (int ss = 0; ss < 8; ++ss) {
            float4 v = *(const float4*)&es[sub * 8 + ss][i];
            acc[ss] += v.x * w0 + v.y * w1 + v.z * w2 + v.w * w3;
        }
    }
#pragma unroll
    for (int ss = 0; ss < 8; ++ss) ts[sub * 8 + ss][j] = leaky(acc[ss]);
    __syncthreads();

    bb = b2[j];
#pragma unroll
    for (int ss = 0; ss < 8; ++ss) acc[ss] = bb;
    for (int i = 0; i < D; i += 4) {
        float w0 = w2T[(i + 0) * D + j];
        float w1 = w2T[(i + 1) * D + j];
        float w2v = w2T[(i + 2) * D + j];
        float w3 = w2T[(i + 3) * D + j];
#pragma unroll
        for (int ss = 0; ss < 8; ++ss) {
            float4 v = *(const float4*)&ts[sub * 8 + ss][i];
            acc[ss] += v.x * w0 + v.y * w1 + v.z * w2v + v.w * w3;
        }
    }
#pragma unroll
    for (int ss = 0; ss < 8; ++ss) {
        int n = n0 + sub * 8 + ss;
        hF[n * D + j] = acc[ss];
    }
}

// ---------------- initial P = h0 @ bond^T  (one 16-row tile per block, 1 wave) ----------------
__global__ __launch_bounds__(64) void k_p0(
    const float* __restrict__ hF, const half_t* __restrict__ bondTP,
    float* __restrict__ P) {
    __shared__ __align__(16) half_t As[MT * LDA];
    int lane = threadIdx.x;
    int quad = lane >> 4, l16 = lane & 15;
    int n0 = blockIdx.x * MT;
#pragma unroll
    for (int t = 0; t < 8; ++t) {
        int idx = t * 64 + lane;         // 512 float4-groups of 4
        int row = idx >> 5;
        int col = (idx & 31) * 4;
        float4 v = *(const float4*)(hF + (size_t)(n0 + row) * D + col);
        f16x4 hv;
        hv[0] = (half_t)v.x; hv[1] = (half_t)v.y; hv[2] = (half_t)v.z; hv[3] = (half_t)v.w;
        *(f16x4*)&As[row * LDA + col] = hv;
    }
    __syncthreads();
#pragma unroll
    for (int nt = 0; nt < 2; ++nt) {
        f32x4 acc = {0.f, 0.f, 0.f, 0.f};
#pragma unroll
        for (int kt = 0; kt < 4; ++kt) {
            f16x8 b = *(const f16x8*)(bondTP + (size_t)((nt * 4 + kt) * 64 + lane) * 8);
            f16x8 a = *(const f16x8*)&As[l16 * LDA + kt * 32 + quad * 8];
            acc = __builtin_amdgcn_mfma_f32_16x16x32_f16(a, b, acc, 0, 0, 0);
        }
#pragma unroll
        for (int r = 0; r < 4; ++r)
            P[(size_t)(n0 + quad * 4 + r) * 32 + nt * 16 + l16] = acc[r];
    }
}

// ---------------- one conv+GRU step ----------------
// 512 blocks x 512 threads (8 waves); block owns 16 nodes; wave w owns cols [16w,16w+16).
// Edge messages via P gather: agg_c = sum_e P[src][a0] * bond[a1][c].
// At end (writeP): P_next = h_new @ bond^T fused (waves 0,1).
__global__ __launch_bounds__(512) void k_step(
    float* __restrict__ hF,
    const float* __restrict__ Pprev, float* __restrict__ Pnext,
    const float* __restrict__ bond,
    const half_t* __restrict__ rootP, const half_t* __restrict__ WihP,
    const half_t* __restrict__ WhhP, const half_t* __restrict__ bondTP,
    const float* __restrict__ cbias, const float* __restrict__ bih,
    const float* __restrict__ bhh,
    const int* __restrict__ eidx, const int* __restrict__ eattr,
    const int* __restrict__ row_start, const int* __restrict__ edge_list,
    const float* __restrict__ inv_deg, int writeP) {
    __shared__ __align__(16) half_t As[MT * LDA];
    __shared__ __align__(16) half_t Am[MT * LDA];

    const int tid = threadIdx.x;
    const int w = tid >> 6;
    const int lane = tid & 63;
    const int quad = lane >> 4;
    const int l16 = lane & 15;
    const int n0 = blockIdx.x * MT;
    const int c = w * 16 + l16;

    // --- stage h (fp32 -> fp16) into As ---
    {
        int row = tid >> 5;
        int col = (tid & 31) * 4;
        float4 v = *(const float4*)(hF + (size_t)(n0 + row) * D + col);
        f16x4 hv;
        hv[0] = (half_t)v.x; hv[1] = (half_t)v.y; hv[2] = (half_t)v.z; hv[3] = (half_t)v.w;
        *(f16x4*)&As[row * LDA + col] = hv;
    }
    __syncthreads();

    // --- edge aggregation via scalar P gathers (issued early for latency overlap) ---
    float aggv[4];
#pragma unroll
    for (int r = 0; r < 4; ++r) {
        int node = n0 + quad * 4 + r;
        float a = 0.f;
        int q0 = row_start[node], q1 = row_start[node + 1];
        for (int p = q0; p < q1; ++p) {
            int e = edge_list[p];
            int s2 = eidx[e];
            int2 aa = *(const int2*)(eattr + 2 * e);
            a += Pprev[(size_t)s2 * 32 + aa.x] * bond[aa.y * D + c];
        }
        aggv[r] = a * inv_deg[node];
    }

    // --- conv GEMM: h_tile @ root (wave's 16 cols) ---
    f32x4 convAcc = {0.f, 0.f, 0.f, 0.f};
#pragma unroll
    for (int kt = 0; kt < 4; ++kt) {
        f16x8 b = *(const f16x8*)(rootP + (size_t)((w * 4 + kt) * 64 + lane) * 8);
        f16x8 a = *(const f16x8*)&As[l16 * LDA + kt * 32 + quad * 8];
        convAcc = __builtin_amdgcn_mfma_f32_16x16x32_f16(a, b, convAcc, 0, 0, 0);
    }
    // --- gh GEMM: h_tile @ Whh^T (3 gates) ---
    f32x4 ghA[3] = {{0.f, 0.f, 0.f, 0.f}, {0.f, 0.f, 0.f, 0.f}, {0.f, 0.f, 0.f, 0.f}};
#pragma unroll
    for (int kt = 0; kt < 4; ++kt) {
        f16x8 a = *(const f16x8*)&As[l16 * LDA + kt * 32 + quad * 8];
#pragma unroll
        for (int g = 0; g < 3; ++g) {
            f16x8 b = *(const f16x8*)(WhhP + (size_t)(((g * 8 + w) * 4 + kt) * 64 + lane) * 8);
            ghA[g] = __builtin_amdgcn_mfma_f32_16x16x32_f16(a, b, ghA[g], 0, 0, 0);
        }
    }

    // --- m = leaky(conv + cbias + agg) -> Am ---
    {
        float cb = cbias[c];
#pragma unroll
        for (int r = 0; r < 4; ++r) {
            float m = convAcc[r] + cb + aggv[r];
            Am[(quad * 4 + r) * LDA + c] = (half_t)leaky(m);
        }
    }
    __syncthreads();

    // --- old h for the GRU combine ---
    float hold[4];
#pragma unroll
    for (int r = 0; r < 4; ++r) hold[r] = hF[(size_t)(n0 + quad * 4 + r) * D + c];

    // --- gi GEMM: m_tile @ Wih^T ---
    f32x4 giA[3] = {{0.f, 0.f, 0.f, 0.f}, {0.f, 0.f, 0.f, 0.f}, {0.f, 0.f, 0.f, 0.f}};
#pragma unroll
    for (int kt = 0; kt < 4; ++kt) {
        f16x8 a = *(const f16x8*)&Am[l16 * LDA + kt * 32 + quad * 8];
#pragma unroll
        for (int g = 0; g < 3; ++g) {
            f16x8 b = *(const f16x8*)(WihP + (size_t)(((g * 8 + w) * 4 + kt) * 64 + lane) * 8);
            giA[g] = __builtin_amdgcn_mfma_f32_16x16x32_f16(a, b, giA[g], 0, 0, 0);
        }
    }

    // --- GRU combine; write hF (in place) and As (for fused P_next) ---
    {
        float bi0 = bih[c], bi1 = bih[D + c], bi2 = bih[2 * D + c];
        float bh0 = bhh[c], bh1 = bhh[D + c], bh2 = bhh[2 * D + c];
#pragma unroll
        for (int r = 0; r < 4; ++r) {
            int row = quad * 4 + r;
            float rg = fast_sigmoid(giA[0][r] + bi0 + ghA[0][r] + bh0);
            float z = fast_sigmoid(giA[1][r] + bi1 + ghA[1][r] + bh1);
            float nn = fast_tanh(giA[2][r] + bi2 + rg * (ghA[2][r] + bh2));
            float hnew = (1.f - z) * nn + z * hold[r];
            hF[(size_t)(n0 + row) * D + c] = hnew;
            As[row * LDA + c] = (half_t)hnew;
        }
    }

    if (writeP) {
        __syncthreads();
        if (w < 2) {   // waves 0,1: P_next tile (16 rows x 32 stemtypes)
            f32x4 acc = {0.f, 0.f, 0.f, 0.f};
#pragma unroll
            for (int kt = 0; kt < 4; ++kt) {
                f16x8 b = *(const f16x8*)(bondTP + (size_t)((w * 4 + kt) * 64 + lane) * 8);
                f16x8 a = *(const f16x8*)&As[l16 * LDA + kt * 32 + quad * 8];
                acc = __builtin_amdgcn_mfma_f32_16x16x32_f16(a, b, acc, 0, 0, 0);
            }
#pragma unroll
            for (int r = 0; r < 4; ++r)
                Pnext[(size_t)(n0 + quad * 4 + r) * 32 + w * 16 + l16] = acc[r];
        }
    }
}

// ---------------- stem head (fp32) ----------------
__global__ __launch_bounds__(256) void k_stem(
    const float* __restrict__ out0, const int* __restrict__ sni, const int* __restrict__ stypes,
    const float* __restrict__ embStem,
    const float* __restrict__ w1T, const float* __restrict__ b1,
    const float* __restrict__ w2T, const float* __restrict__ b2,
    const float* __restrict__ w3T, const float* __restrict__ b3,
    float* __restrict__ dout) {
    __shared__ float cat[16][2 * D];
    __shared__ float s1[16][D];
    __shared__ float s2[16][D];
    int tid = threadIdx.x;
    int j = tid & 127;
    int sub = tid >> 7;
    int s0 = blockIdx.x * 16;

    for (int ss = 0; ss < 16; ++ss) {
        int s = s0 + ss;
        if (tid < 128) cat[ss][tid] = out0[sni[s] * D + tid];
        else cat[ss][tid] = embStem[stypes[s] * D + (tid - 128)];
    }
    __syncthreads();

    float acc[8];
    {
        float bb = b1[j];
#pragma unroll
        for (int ss = 0; ss < 8; ++ss) acc[ss] = bb;
        for (int i = 0; i < 2 * D; i += 4) {
            float w0 = w1T[(i + 0) * D + j];
            float w1 = w1T[(i + 1) * D + j];
            float w2 = w1T[(i + 2) * D + j];
            float w3 = w1T[(i + 3) * D + j];
#pragma unroll
            for (int ss = 0; ss < 8; ++ss) {
                float4 v = *(const float4*)&cat[sub * 8 + ss][i];
                acc[ss] += v.x * w0 + v.y * w1 + v.z * w2 + v.w * w3;
            }
        }
#pragma unroll
        for (int ss = 0; ss < 8; ++ss) s1[sub * 8 + ss][j] = leaky(acc[ss]);
    }
    __syncthreads();
    {
        float bb = b2[j];
#pragma unroll
        for (int ss = 0; ss < 8; ++ss) acc[ss] = bb;
        for (int i = 0; i < D; i += 4) {
            float w0 = w2T[(i + 0) * D + j];
            float w1 = w2T[(i + 1) * D + j];
            float w2 = w2T[(i + 2) * D + j];
            float w3 = w2T[(i + 3) * D + j];
#pragma unroll
            for (int ss = 0; ss < 8; ++ss) {
                float4 v = *(const float4*)&s1[sub * 8 + ss][i];
                acc[ss] += v.x * w0 + v.y * w1 + v.z * w2 + v.w * w3;
            }
        }
#pragma unroll
        for (int ss = 0; ss < 8; ++ss) s2[sub * 8 + ss][j] = leaky(acc[ss]);
    }
    __syncthreads();
    if (j < OPS) {
        float bb = b3[j];
#pragma unroll
        for (int ss = 0; ss < 8; ++ss) acc[ss] = bb;
        for (int i = 0; i < D; i += 4) {
            float w0 = w3T[(i + 0) * OPS + j];
            float w1 = w3T[(i + 1) * OPS + j];
            float w2 = w3T[(i + 2) * OPS + j];
            float w3 = w3T[(i + 3) * OPS + j];
#pragma unroll
            for (int ss = 0; ss < 8; ++ss) {
                float4 v = *(const float4*)&s2[sub * 8 + ss][i];
                acc[ss] += v.x * w0 + v.y * w1 + v.z * w2 + v.w * w3;
            }
        }
#pragma unroll
        for (int ss = 0; ss < 8; ++ss) {
            int s = s0 + sub * 8 + ss;
            dout[s * OPS + j] = acc[ss];
        }
    }
}

// ---------------- global mean pool + stop head (sorted segments) ----------------
__device__ __forceinline__ int lower_bound_dev(const int* a, int n, int v) {
    int lo = 0, hi = n;
    while (lo < hi) {
        int m = (lo + hi) >> 1;
        if (a[m] < v) lo = m + 1;
        else hi = m;
    }
    return lo;
}

__global__ __launch_bounds__(128) void k_gpred(
    const float* __restrict__ hF, const int* __restrict__ batch,
    const float* __restrict__ g1T, const float* __restrict__ b1,
    const float* __restrict__ w2, const float* __restrict__ b2,
    float* __restrict__ dout) {
    __shared__ float mean_s[D];
    __shared__ float red[D];
    int g = blockIdx.x;
    int j = threadIdx.x;
    int lo = lower_bound_dev(batch, NNODES, g);
    int hi = lower_bound_dev(batch, NNODES, g + 1);
    float sum = 0.f;
    for (int n = lo; n < hi; ++n) sum += hF[(size_t)n * D + j];
    float denom = (hi > lo) ? (float)(hi - lo) : 1.0f;
    mean_s[j] = sum / denom;
    __syncthreads();
    float a = b1[j];
    for (int i = 0; i < D; ++i) a += mean_s[i] * g1T[i * D + j];
    a = leaky(a);
    red[j] = a * w2[j];
    __syncthreads();
    for (int off = 64; off > 0; off >>= 1) {
        if (j < off) red[j] += red[j + off];
        __syncthreads();
    }
    if (j == 0) dout[NSTEMS * OPS + g] = red[0] + b2[0];
}

// ---------------- launch ----------------
extern "C" void kernel_launch(void* const* d_in, const int* in_sizes, int n_in,
                              void* d_out, int out_size, void* d_ws, size_t ws_size,
                              hipStream_t stream) {
    const int* x = (const int*)d_in[0];
    const int* stypes = (const int*)d_in[1];
    const int* eattr = (const int*)d_in[2];
    const int* eidx = (const int*)d_in[3];
    const int* sni = (const int*)d_in[4];
    const int* batch = (const int*)d_in[5];
    const float* embBlock = (const float*)d_in[6];
    const float* embStem = (const float*)d_in[7];
    const float* embBond = (const float*)d_in[8];
    const float* b2e_w1 = (const float*)d_in[9];
    const float* b2e_b1 = (const float*)d_in[10];
    const float* b2e_w2 = (const float*)d_in[11];
    const float* b2e_b2 = (const float*)d_in[12];
    const float* conv_root = (const float*)d_in[13];
    const float* conv_bias = (const float*)d_in[14];
    const float* gru_w_ih = (const float*)d_in[15];
    const float* gru_w_hh = (const float*)d_in[16];
    const float* gru_b_ih = (const float*)d_in[17];
    const float* gru_b_hh = (const float*)d_in[18];
    const float* s2p_w1 = (const float*)d_in[19];
    const float* s2p_b1 = (const float*)d_in[20];
    const float* s2p_w2 = (const float*)d_in[21];
    const float* s2p_b2 = (const float*)d_in[22];
    const float* s2p_w3 = (const float*)d_in[23];
    const float* s2p_b3 = (const float*)d_in[24];
    const float* g2p_w1 = (const float*)d_in[25];
    const float* g2p_b1 = (const float*)d_in[26];
    const float* g2p_w2 = (const float*)d_in[27];
    const float* g2p_b2 = (const float*)d_in[28];
    float* out_f = (float*)d_out;

    float* W = (float*)d_ws;
    size_t off = 0;
    auto alloc = [&](size_t words) {
        size_t o = off;
        off += (words + 3) & ~(size_t)3;
        return o;
    };
    float* hF = W + alloc(NNODES * D);
    float* P0 = W + alloc(NNODES * 32);
    float* P1 = W + alloc(NNODES * 32);
    half_t* rootP = (half_t*)(W + alloc(8 * 4 * 512 / 2));
    half_t* WihP = (half_t*)(W + alloc(24 * 4 * 512 / 2));
    half_t* WhhP = (half_t*)(W + alloc(24 * 4 * 512 / 2));
    half_t* bondTP = (half_t*)(W + alloc(2 * 4 * 512 / 2));
    float* w1T = W + alloc(128 * 128);
    float* w2T = W + alloc(128 * 128);
    float* s1T = W + alloc(256 * 128);
    float* s2T = W + alloc(128 * 128);
    float* s3T = W + alloc(128 * 105);
    float* g1T = W + alloc(128 * 128);
    int* row_start = (int*)(W + alloc(NNODES + 1));
    int* edge_list = (int*)(W + alloc(NEDGES));
    float* inv_deg = W + alloc(NNODES);
    const int zwords = NNODES + NNODES;   // deg + fill
    float* zbase = W + alloc(zwords);
    int* deg = (int*)zbase;
    int* fill = deg + NNODES;

    k_zero<<<(zwords + 255) / 256, 256, 0, stream>>>(zbase, zwords);
    k_transpose_all<<<dim3(128, 6), 256, 0, stream>>>(
        b2e_w1, b2e_w2, s2p_w1, s2p_w2, s2p_w3, g2p_w1,
        w1T, w2T, s1T, s2T, s3T, g1T);
    k_pack<<<dim3(192, 4), 256, 0, stream>>>(conv_root, gru_w_ih, gru_w_hh, embBond,
                                             rootP, WihP, WhhP, bondTP);
    k_deg<<<(NEDGES + 255) / 256, 256, 0, stream>>>(eidx, deg);
    k_scan<<<1, 256, 0, stream>>>(deg, row_start, inv_deg);
    k_scatter<<<(NEDGES + 255) / 256, 256, 0, stream>>>(eidx, row_start, fill, edge_list);
    k_init<<<NNODES / 16, 256, 0, stream>>>(x, embBlock, w1T, b2e_b1, w2T, b2e_b2, hF);
    k_p0<<<NB, 64, 0, stream>>>(hF, bondTP, P0);

    for (int step = 0; step < NSTEPS; ++step) {
        const float* Pprev = (step & 1) ? P1 : P0;
        float* Pnext = (step & 1) ? P0 : P1;
        int writeP = (step < NSTEPS - 1) ? 1 : 0;
        k_step<<<NB, 512, 0, stream>>>(
            hF, Pprev, Pnext, embBond, rootP, WihP, WhhP, bondTP,
            conv_bias, gru_b_ih, gru_b_hh,
            eidx, eattr, row_start, edge_list, inv_deg, writeP);
    }

    k_stem<<<NSTEMS / 16, 256, 0, stream>>>(hF, sni, stypes, embStem,
                                            s1T, s2p_b1, s2T, s2p_b2, s3T, s2p_b3, out_f);
    k_gpred<<<NGRAPHS, 128, 0, stream>>>(hF, batch, g1T, g2p_b1, g2p_w2, g2p_b2, out_f);
}

// Round 5
// 323.202 us; speedup vs baseline: 4.8226x; 1.3095x over previous
//
#include <hip/hip_runtime.h>
#include <math.h>

#define D 128
#define NNODES 8192
#define NEDGES 16384
#define NSTEMS 4096
#define NGRAPHS 256
#define NSTEPS 12
#define OPS 105
#define SLOPE 0.01f
#define MT 16              // nodes per step-block
#define NB (NNODES / MT)   // 512 blocks -> 2 blocks/CU
#define LDA 136            // padded halfs per LDS row (h/m tiles)
#define LDA2 264           // padded halfs per LDS row (stem cat tile, 256 cols)
#define EMAX 512           // per-block edge cap for the LDS fast path

typedef _Float16 half_t;
typedef __attribute__((ext_vector_type(8))) _Float16 f16x8;
typedef __attribute__((ext_vector_type(4))) _Float16 f16x4;
typedef __attribute__((ext_vector_type(4))) float f32x4;

__device__ __forceinline__ float leaky(float x) { return x > 0.f ? x : SLOPE * x; }
__device__ __forceinline__ float fast_sigmoid(float x) {
    return __builtin_amdgcn_rcpf(1.f + __expf(-x));
}
__device__ __forceinline__ float fast_tanh(float x) {
    float e = __expf(2.f * x);
    return 1.f - 2.f * __builtin_amdgcn_rcpf(e + 1.f);
}

// ---------------- setup kernels ----------------

__global__ void k_zero(float* p, int n) {
    int i = blockIdx.x * 256 + threadIdx.x;
    if (i < n) p[i] = 0.f;
}

__global__ void k_deg(const int* __restrict__ eidx, int* __restrict__ deg) {
    int e = blockIdx.x * 256 + threadIdx.x;
    if (e < NEDGES) atomicAdd(&deg[eidx[NEDGES + e]], 1);
}

__global__ void k_scan(const int* __restrict__ deg, int* __restrict__ row_start,
                       float* __restrict__ inv_deg) {
    __shared__ int sums[256];
    int t = threadIdx.x;
    int base = t * 32;
    int s = 0;
    for (int k = 0; k < 32; ++k) s += deg[base + k];
    sums[t] = s;
    __syncthreads();
    for (int off = 1; off < 256; off <<= 1) {
        int v = sums[t];
        int u = (t >= off) ? sums[t - off] : 0;
        __syncthreads();
        sums[t] = v + u;
        __syncthreads();
    }
    int run = sums[t] - s;
    for (int k = 0; k < 32; ++k) {
        int d = deg[base + k];
        row_start[base + k] = run;
        run += d;
        inv_deg[base + k] = (d > 0) ? (1.0f / (float)d) : 0.0f;
    }
    if (t == 255) row_start[NNODES] = run;
}

// CSR-ordered packed edges: epack[pos] = {src, a0, a1, 0}
__global__ void k_scatter(const int* __restrict__ eidx, const int* __restrict__ eattr,
                          const int* __restrict__ row_start,
                          int* __restrict__ fill, int4* __restrict__ epack) {
    int e = blockIdx.x * 256 + threadIdx.x;
    if (e < NEDGES) {
        int d = eidx[NEDGES + e];
        int pos = row_start[d] + atomicAdd(&fill[d], 1);
        int2 aa = *(const int2*)(eattr + 2 * e);
        epack[pos] = make_int4(eidx[e], aa.x, aa.y, 0);
    }
}

__device__ __forceinline__ void tr(const float* __restrict__ src, float* __restrict__ dst,
                                   int rows, int cols, int idx) {
    if (idx < rows * cols) {
        int r = idx / cols;
        int c = idx - r * cols;
        dst[c * rows + r] = src[idx];
    }
}

__global__ void k_transpose_all(
    const float* bw1, const float* bw2, const float* gw1,
    float* w1T, float* w2T, float* g1T) {
    int idx = blockIdx.x * 256 + threadIdx.x;
    switch (blockIdx.y) {
        case 0: tr(bw1, w1T, 128, 128, idx); break;
        case 1: tr(bw2, w2T, 128, 128, idx); break;
        case 2: tr(gw1, g1T, 128, 128, idx); break;
    }
}

// Pack weights into MFMA B-fragment order, fp16.
// B-frag 16x16x32: lane L supplies B[k = kt*32 + (L>>4)*8 + j][n = nt*16 + (L&15)], j=0..7.
// idx = ((nt*KT + kt)*64 + L)*8 + j
__global__ void k_pack(const float* __restrict__ root, const float* __restrict__ wih,
                       const float* __restrict__ whh, const float* __restrict__ bond,
                       const float* __restrict__ sw1, const float* __restrict__ sw2,
                       const float* __restrict__ sw3,
                       half_t* __restrict__ rootP, half_t* __restrict__ WihP,
                       half_t* __restrict__ WhhP, half_t* __restrict__ bondTP,
                       half_t* __restrict__ s1P, half_t* __restrict__ s2P,
                       half_t* __restrict__ s3P) {
    int idx = blockIdx.x * 256 + threadIdx.x;
    int which = blockIdx.y;
    int KT = (which == 4) ? 8 : 4;
    int NT = (which == 0) ? 8 : (which == 1 || which == 2) ? 24 :
             (which == 3) ? 2 : (which == 4 || which == 5) ? 8 : 7;
    if (idx >= NT * KT * 512) return;
    int j = idx & 7;
    int L = (idx >> 3) & 63;
    int t = idx >> 9;
    int kt = t % KT, nt = t / KT;
    int k = kt * 32 + (L >> 4) * 8 + j;
    int n = nt * 16 + (L & 15);
    switch (which) {
        case 0: rootP[idx] = (half_t)root[k * D + n]; break;        // B[k][n]=root[k][n]
        case 1: WihP[idx] = (half_t)wih[n * D + k]; break;          // B[k][n]=wih[n][k]
        case 2: WhhP[idx] = (half_t)whh[n * D + k]; break;
        case 3: bondTP[idx] = (half_t)bond[n * D + k]; break;       // P = h @ bond^T
        case 4: s1P[idx] = (half_t)sw1[n * 256 + k]; break;         // stem L1, K=256
        case 5: s2P[idx] = (half_t)sw2[n * 128 + k]; break;
        case 6: s3P[idx] = (n < OPS) ? (half_t)sw3[n * 128 + k] : (half_t)0.f; break;
    }
}

// ---------------- node init: h0 = act(emb@W1.T+b1)@W2.T+b2 (fp32) ----------------
__global__ __launch_bounds__(256) void k_init(
    const int* __restrict__ x, const float* __restrict__ embBlock,
    const float* __restrict__ w1T, const float* __restrict__ b1,
    const float* __restrict__ w2T, const float* __restrict__ b2,
    float* __restrict__ hF) {
    __shared__ float es[16][D];
    __shared__ float ts[16][D];
    int tid = threadIdx.x;
    int j = tid & 127;
    int sub = tid >> 7;
    int n0 = blockIdx.x * 16;

    for (int ss = 0; ss < 8; ++ss) {
        int nn = sub * 8 + ss;
        es[nn][j] = embBlock[x[n0 + nn] * D + j];
    }
    __syncthreads();

    float acc[8];
    float bb = b1[j];
#pragma unroll
    for (int ss = 0; ss < 8; ++ss) acc[ss] = bb;
    for (int i = 0; i < D; i += 4) {
        float w0 = w1T[(i + 0) * D + j];
        float w1 = w1T[(i + 1) * D + j];
        float w2 = w1T[(i + 2) * D + j];
        float w3 = w1T[(i + 3) * D + j];
#pragma unroll
        for (int ss = 0; ss < 8; ++ss) {
            float4 v = *(const float4*)&es[sub * 8 + ss][i];
            acc[ss] += v.x * w0 + v.y * w1 + v.z * w2 + v.w * w3;
        }
    }
#pragma unroll
    for (int ss = 0; ss < 8; ++ss) ts[sub * 8 + ss][j] = leaky(acc[ss]);
    __syncthreads();

    bb = b2[j];
#pragma unroll
    for (int ss = 0; ss < 8; ++ss) acc[ss] = bb;
    for (int i = 0; i < D; i += 4) {
        float w0 = w2T[(i + 0) * D + j];
        float w1 = w2T[(i + 1) * D + j];
        float w2v = w2T[(i + 2) * D + j];
        float w3 = w2T[(i + 3) * D + j];
#pragma unroll
        for (int ss = 0; ss < 8; ++ss) {
            float4 v = *(const float4*)&ts[sub * 8 + ss][i];
            acc[ss] += v.x * w0 + v.y * w1 + v.z * w2v + v.w * w3;
        }
    }
#pragma unroll
    for (int ss = 0; ss < 8; ++ss) {
        int n = n0 + sub * 8 + ss;
        hF[n * D + j] = acc[ss];
    }
}

// ---------------- initial P = h0 @ bond^T ----------------
__global__ __launch_bounds__(64) void k_p0(
    const float* __restrict__ hF, const half_t* __restrict__ bondTP,
    float* __restrict__ P) {
    __shared__ __align__(16) half_t As[MT * LDA];
    int lane = threadIdx.x;
    int quad = lane >> 4, l16 = lane & 15;
    int n0 = blockIdx.x * MT;
#pragma unroll
    for (int t = 0; t < 8; ++t) {
        int idx = t * 64 + lane;
        int row = idx >> 5;
        int col = (idx & 31) * 4;
        float4 v = *(const float4*)(hF + (size_t)(n0 + row) * D + col);
        f16x4 hv;
        hv[0] = (half_t)v.x; hv[1] = (half_t)v.y; hv[2] = (half_t)v.z; hv[3] = (half_t)v.w;
        *(f16x4*)&As[row * LDA + col] = hv;
    }
    __syncthreads();
#pragma unroll
    for (int nt = 0; nt < 2; ++nt) {
        f32x4 acc = {0.f, 0.f, 0.f, 0.f};
#pragma unroll
        for (int kt = 0; kt < 4; ++kt) {
            f16x8 b = *(const f16x8*)(bondTP + (size_t)((nt * 4 + kt) * 64 + lane) * 8);
            f16x8 a = *(const f16x8*)&As[l16 * LDA + kt * 32 + quad * 8];
            acc = __builtin_amdgcn_mfma_f32_16x16x32_f16(a, b, acc, 0, 0, 0);
        }
#pragma unroll
        for (int r = 0; r < 4; ++r)
            P[(size_t)(n0 + quad * 4 + r) * 32 + nt * 16 + l16] = acc[r];
    }
}

// ---------------- one conv+GRU step ----------------
// 512 blocks x 512 threads (8 waves); block owns 16 nodes; wave w owns cols [16w,16w+16).
// Edge phase: depth-1 gather w_e = Pprev[src*32+a0] (one thread per edge, hidden
// under the conv/gh MFMAs), then per-node aggregation entirely from LDS.
__global__ __launch_bounds__(512) void k_step(
    float* __restrict__ hF,
    const float* __restrict__ Pprev, float* __restrict__ Pnext,
    const float* __restrict__ bond,
    const half_t* __restrict__ rootP, const half_t* __restrict__ WihP,
    const half_t* __restrict__ WhhP, const half_t* __restrict__ bondTP,
    const float* __restrict__ cbias, const float* __restrict__ bih,
    const float* __restrict__ bhh,
    const int4* __restrict__ epack,
    const int* __restrict__ row_start, const float* __restrict__ inv_deg, int writeP) {
    __shared__ __align__(16) half_t As[MT * LDA];
    __shared__ __align__(16) half_t Am[MT * LDA];
    __shared__ float bondS[32 * D];      // full bond table, fp32 (16 KB)
    __shared__ float ws[EMAX];           // per-edge P value
    __shared__ int ea1[EMAX];            // per-edge a1

    const int tid = threadIdx.x;
    const int w = tid >> 6;
    const int lane = tid & 63;
    const int quad = lane >> 4;
    const int l16 = lane & 15;
    const int n0 = blockIdx.x * MT;
    const int c = w * 16 + l16;

    // --- stage h (fp32 -> fp16) into As; stage bond into LDS ---
    {
        int row = tid >> 5;
        int col = (tid & 31) * 4;
        float4 v = *(const float4*)(hF + (size_t)(n0 + row) * D + col);
        f16x4 hv;
        hv[0] = (half_t)v.x; hv[1] = (half_t)v.y; hv[2] = (half_t)v.z; hv[3] = (half_t)v.w;
        *(f16x4*)&As[row * LDA + col] = hv;
    }
#pragma unroll
    for (int i = tid; i < 32 * D / 4; i += 512)
        *(float4*)&bondS[i * 4] = ((const float4*)bond)[i];
    const int p0 = row_start[n0];
    const int p1 = row_start[n0 + MT];
    const int ne = p1 - p0;
    const int nec = ne < EMAX ? ne : EMAX;
    __syncthreads();

    // --- phase 1: issue this thread's edge gather (depth-1 chain) ---
    int4 ep;
    float wv = 0.f;
    const bool have = (tid < nec);
    if (have) {
        ep = epack[p0 + tid];
        wv = Pprev[(size_t)ep.x * 32 + ep.y];
    }

    // --- conv GEMM: h_tile @ root (wave's 16 cols) — hides phase-1 latency ---
    f32x4 convAcc = {0.f, 0.f, 0.f, 0.f};
#pragma unroll
    for (int kt = 0; kt < 4; ++kt) {
        f16x8 b = *(const f16x8*)(rootP + (size_t)((w * 4 + kt) * 64 + lane) * 8);
        f16x8 a = *(const f16x8*)&As[l16 * LDA + kt * 32 + quad * 8];
        convAcc = __builtin_amdgcn_mfma_f32_16x16x32_f16(a, b, convAcc, 0, 0, 0);
    }
    // --- gh GEMM: h_tile @ Whh^T (3 gates) ---
    f32x4 ghA[3] = {{0.f, 0.f, 0.f, 0.f}, {0.f, 0.f, 0.f, 0.f}, {0.f, 0.f, 0.f, 0.f}};
#pragma unroll
    for (int kt = 0; kt < 4; ++kt) {
        f16x8 a = *(const f16x8*)&As[l16 * LDA + kt * 32 + quad * 8];
#pragma unroll
        for (int g = 0; g < 3; ++g) {
            f16x8 b = *(const f16x8*)(WhhP + (size_t)(((g * 8 + w) * 4 + kt) * 64 + lane) * 8);
            ghA[g] = __builtin_amdgcn_mfma_f32_16x16x32_f16(a, b, ghA[g], 0, 0, 0);
        }
    }

    // --- phase-1 results to LDS ---
    if (have) {
        ws[tid] = wv;
        ea1[tid] = ep.z;
    }
    __syncthreads();

    // --- phase 2: per-node aggregation from LDS; m = leaky(conv + cbias + agg) ---
    {
        float cb = cbias[c];
#pragma unroll
        for (int r = 0; r < 4; ++r) {
            int node = n0 + quad * 4 + r;
            float a = 0.f;
            int q0 = row_start[node], q1 = row_start[node + 1];
            for (int p = q0; p < q1; ++p) {
                int rel = p - p0;
                if (rel < EMAX) {
                    a += ws[rel] * bondS[ea1[rel] * D + c];
                } else {   // overflow fallback (never expected)
                    int4 e2 = epack[p];
                    a += Pprev[(size_t)e2.x * 32 + e2.y] * bond[e2.z * D + c];
                }
            }
            float m = convAcc[r] + cb + a * inv_deg[node];
            Am[(quad * 4 + r) * LDA + c] = (half_t)leaky(m);
        }
    }
    __syncthreads();

    // --- old h for the GRU combine ---
    float hold[4];
#pragma unroll
    for (int r = 0; r < 4; ++r) hold[r] = hF[(size_t)(n0 + quad * 4 + r) * D + c];

    // --- gi GEMM: m_tile @ Wih^T ---
    f32x4 giA[3] = {{0.f, 0.f, 0.f, 0.f}, {0.f, 0.f, 0.f, 0.f}, {0.f, 0.f, 0.f, 0.f}};
#pragma unroll
    for (int kt = 0; kt < 4; ++kt) {
        f16x8 a = *(const f16x8*)&Am[l16 * LDA + kt * 32 + quad * 8];
#pragma unroll
        for (int g = 0; g < 3; ++g) {
            f16x8 b = *(const f16x8*)(WihP + (size_t)(((g * 8 + w) * 4 + kt) * 64 + lane) * 8);
            giA[g] = __builtin_amdgcn_mfma_f32_16x16x32_f16(a, b, giA[g], 0, 0, 0);
        }
    }

    // --- GRU combine; write hF (in place) and As (for fused P_next) ---
    {
        float bi0 = bih[c], bi1 = bih[D + c], bi2 = bih[2 * D + c];
        float bh0 = bhh[c], bh1 = bhh[D + c], bh2 = bhh[2 * D + c];
#pragma unroll
        for (int r = 0; r < 4; ++r) {
            int row = quad * 4 + r;
            float rg = fast_sigmoid(giA[0][r] + bi0 + ghA[0][r] + bh0);
            float z = fast_sigmoid(giA[1][r] + bi1 + ghA[1][r] + bh1);
            float nn = fast_tanh(giA[2][r] + bi2 + rg * (ghA[2][r] + bh2));
            float hnew = (1.f - z) * nn + z * hold[r];
            hF[(size_t)(n0 + row) * D + c] = hnew;
            As[row * LDA + c] = (half_t)hnew;
        }
    }

    if (writeP) {
        __syncthreads();
        if (w < 2) {
            f32x4 acc = {0.f, 0.f, 0.f, 0.f};
#pragma unroll
            for (int kt = 0; kt < 4; ++kt) {
                f16x8 b = *(const f16x8*)(bondTP + (size_t)((w * 4 + kt) * 64 + lane) * 8);
                f16x8 a = *(const f16x8*)&As[l16 * LDA + kt * 32 + quad * 8];
                acc = __builtin_amdgcn_mfma_f32_16x16x32_f16(a, b, acc, 0, 0, 0);
            }
#pragma unroll
            for (int r = 0; r < 4; ++r)
                Pnext[(size_t)(n0 + quad * 4 + r) * 32 + w * 16 + l16] = acc[r];
        }
    }
}

// ---------------- stem head, MFMA fp16 ----------------
// 256 blocks x 512 threads; 16 stems/block; wave w owns cols [16w,16w+16).
__global__ __launch_bounds__(512) void k_stem(
    const float* __restrict__ hF, const int* __restrict__ sni, const int* __restrict__ stypes,
    const float* __restrict__ embStem,
    const half_t* __restrict__ s1P, const float* __restrict__ b1,
    const half_t* __restrict__ s2P, const float* __restrict__ b2,
    const half_t* __restrict__ s3P, const float* __restrict__ b3,
    float* __restrict__ dout) {
    __shared__ __align__(16) half_t cat[16 * LDA2];   // 16 x 256 (padded)
    __shared__ __align__(16) half_t t1[16 * LDA];
    __shared__ __align__(16) half_t t2[16 * LDA];
    const int tid = threadIdx.x;
    const int w = tid >> 6;
    const int lane = tid & 63;
    const int quad = lane >> 4;
    const int l16 = lane & 15;
    const int s0 = blockIdx.x * 16;
    const int c = w * 16 + l16;

    // --- stage cat = [h[sni], embStem[stype]] fp32->fp16 ---
    {
        int row = tid >> 5;
        int col = (tid & 31) * 8;
        const float* src;
        if (col < D) src = hF + (size_t)sni[s0 + row] * D + col;
        else src = embStem + (size_t)stypes[s0 + row] * D + (col - D);
        float4 v0 = ((const float4*)src)[0];
        float4 v1 = ((const float4*)src)[1];
        f16x8 hv;
        hv[0] = (half_t)v0.x; hv[1] = (half_t)v0.y; hv[2] = (half_t)v0.z; hv[3] = (half_t)v0.w;
        hv[4] = (half_t)v1.x; hv[5] = (half_t)v1.y; hv[6] = (half_t)v1.z; hv[7] = (half_t)v1.w;
        *(f16x8*)&cat[row * LDA2 + col] = hv;
    }
    __syncthreads();

    // --- L1: cat @ W1^T (K=256), leaky -> t1 ---
    {
        f32x4 acc = {0.f, 0.f, 0.f, 0.f};
#pragma unroll
        for (int kt = 0; kt < 8; ++kt) {
            f16x8 b = *(const f16x8*)(s1P + (size_t)((w * 8 + kt) * 64 + lane) * 8);
            f16x8 a = *(const f16x8*)&cat[l16 * LDA2 + kt * 32 + quad * 8];
            acc = __builtin_amdgcn_mfma_f32_16x16x32_f16(a, b, acc, 0, 0, 0);
        }
        float bb = b1[c];
#pragma unroll
        for (int r = 0; r < 4; ++r)
            t1[(quad * 4 + r) * LDA + c] = (half_t)leaky(acc[r] + bb);
    }
    __syncthreads();

    // --- L2: t1 @ W2^T (K=128), leaky -> t2 ---
    {
        f32x4 acc = {0.f, 0.f, 0.f, 0.f};
#pragma unroll
        for (int kt = 0; kt < 4; ++kt) {
            f16x8 b = *(const f16x8*)(s2P + (size_t)((w * 4 + kt) * 64 + lane) * 8);
            f16x8 a = *(const f16x8*)&t1[l16 * LDA + kt * 32 + quad * 8];
            acc = __builtin_amdgcn_mfma_f32_16x16x32_f16(a, b, acc, 0, 0, 0);
        }
        float bb = b2[c];
#pragma unroll
        for (int r = 0; r < 4; ++r)
            t2[(quad * 4 + r) * LDA + c] = (half_t)leaky(acc[r] + bb);
    }
    __syncthreads();

    // --- L3: t2 @ W3^T (N=105, padded 112): waves 0..6 ---
    if (w < 7) {
        f32x4 acc = {0.f, 0.f, 0.f, 0.f};
#pragma unroll
        for (int kt = 0; kt < 4; ++kt) {
            f16x8 b = *(const f16x8*)(s3P + (size_t)((w * 4 + kt) * 64 + lane) * 8);
            f16x8 a = *(const f16x8*)&t2[l16 * LDA + kt * 32 + quad * 8];
            acc = __builtin_amdgcn_mfma_f32_16x16x32_f16(a, b, acc, 0, 0, 0);
        }
        int j = w * 16 + l16;
        if (j < OPS) {
            float bb = b3[j];
#pragma unroll
            for (int r = 0; r < 4; ++r)
                dout[(size_t)(s0 + quad * 4 + r) * OPS + j] = acc[r] + bb;
        }
    }
}

// ---------------- global mean pool + stop head (sorted segments) ----------------
__device__ __forceinline__ int lower_bound_dev(const int* a, int n, int v) {
    int lo = 0, hi = n;
    while (lo < hi) {
        int m = (lo + hi) >> 1;
        if (a[m] < v) lo = m + 1;
        else hi = m;
    }
    return lo;
}

__global__ __launch_bounds__(128) void k_gpred(
    const float* __restrict__ hF, const int* __restrict__ batch,
    const float* __restrict__ g1T, const float* __restrict__ b1,
    const float* __restrict__ w2, const float* __restrict__ b2,
    float* __restrict__ dout) {
    __shared__ float mean_s[D];
    __shared__ float red[D];
    int g = blockIdx.x;
    int j = threadIdx.x;
    int lo = lower_bound_dev(batch, NNODES, g);
    int hi = lower_bound_dev(batch, NNODES, g + 1);
    float sum = 0.f;
    for (int n = lo; n < hi; ++n) sum += hF[(size_t)n * D + j];
    float denom = (hi > lo) ? (float)(hi - lo) : 1.0f;
    mean_s[j] = sum / denom;
    __syncthreads();
    float a = b1[j];
    for (int i = 0; i < D; ++i) a += mean_s[i] * g1T[i * D + j];
    a = leaky(a);
    red[j] = a * w2[j];
    __syncthreads();
    for (int off = 64; off > 0; off >>= 1) {
        if (j < off) red[j] += red[j + off];
        __syncthreads();
    }
    if (j == 0) dout[NSTEMS * OPS + g] = red[0] + b2[0];
}

// ---------------- launch ----------------
extern "C" void kernel_launch(void* const* d_in, const int* in_sizes, int n_in,
                              void* d_out, int out_size, void* d_ws, size_t ws_size,
                              hipStream_t stream) {
    const int* x = (const int*)d_in[0];
    const int* stypes = (const int*)d_in[1];
    const int* eattr = (const int*)d_in[2];
    const int* eidx = (const int*)d_in[3];
    const int* sni = (const int*)d_in[4];
    const int* batch = (const int*)d_in[5];
    const float* embBlock = (const float*)d_in[6];
    const float* embStem = (const float*)d_in[7];
    const float* embBond = (const float*)d_in[8];
    const float* b2e_w1 = (const float*)d_in[9];
    const float* b2e_b1 = (const float*)d_in[10];
    const float* b2e_w2 = (const float*)d_in[11];
    const float* b2e_b2 = (const float*)d_in[12];
    const float* conv_root = (const float*)d_in[13];
    const float* conv_bias = (const float*)d_in[14];
    const float* gru_w_ih = (const float*)d_in[15];
    const float* gru_w_hh = (const float*)d_in[16];
    const float* gru_b_ih = (const float*)d_in[17];
    const float* gru_b_hh = (const float*)d_in[18];
    const float* s2p_w1 = (const float*)d_in[19];
    const float* s2p_b1 = (const float*)d_in[20];
    const float* s2p_w2 = (const float*)d_in[21];
    const float* s2p_b2 = (const float*)d_in[22];
    const float* s2p_w3 = (const float*)d_in[23];
    const float* s2p_b3 = (const float*)d_in[24];
    const float* g2p_w1 = (const float*)d_in[25];
    const float* g2p_b1 = (const float*)d_in[26];
    const float* g2p_w2 = (const float*)d_in[27];
    const float* g2p_b2 = (const float*)d_in[28];
    float* out_f = (float*)d_out;

    float* W = (float*)d_ws;
    size_t off = 0;
    auto alloc = [&](size_t words) {
        size_t o = off;
        off += (words + 3) & ~(size_t)3;
        return o;
    };
    float* hF = W + alloc(NNODES * D);
    float* P0 = W + alloc(NNODES * 32);
    float* P1 = W + alloc(NNODES * 32);
    half_t* rootP = (half_t*)(W + alloc(8 * 4 * 512 / 2));
    half_t* WihP = (half_t*)(W + alloc(24 * 4 * 512 / 2));
    half_t* WhhP = (half_t*)(W + alloc(24 * 4 * 512 / 2));
    half_t* bondTP = (half_t*)(W + alloc(2 * 4 * 512 / 2));
    half_t* s1P = (half_t*)(W + alloc(8 * 8 * 512 / 2));
    half_t* s2P = (half_t*)(W + alloc(8 * 4 * 512 / 2));
    half_t* s3P = (half_t*)(W + alloc(7 * 4 * 512 / 2));
    float* w1T = W + alloc(128 * 128);
    float* w2T = W + alloc(128 * 128);
    float* g1T = W + alloc(128 * 128);
    int* row_start = (int*)(W + alloc(NNODES + 1));
    int4* epack = (int4*)(W + alloc(NEDGES * 4));
    float* inv_deg = W + alloc(NNODES);
    const int zwords = NNODES + NNODES;   // deg + fill
    float* zbase = W + alloc(zwords);
    int* deg = (int*)zbase;
    int* fill = deg + NNODES;

    k_zero<<<(zwords + 255) / 256, 256, 0, stream>>>(zbase, zwords);
    k_transpose_all<<<dim3(64, 3), 256, 0, stream>>>(b2e_w1, b2e_w2, g2p_w1, w1T, w2T, g1T);
    k_pack<<<dim3(192, 7), 256, 0, stream>>>(conv_root, gru_w_ih, gru_w_hh, embBond,
                                             s2p_w1, s2p_w2, s2p_w3,
                                             rootP, WihP, WhhP, bondTP, s1P, s2P, s3P);
    k_deg<<<(NEDGES + 255) / 256, 256, 0, stream>>>(eidx, deg);
    k_scan<<<1, 256, 0, stream>>>(deg, row_start, inv_deg);
    k_scatter<<<(NEDGES + 255) / 256, 256, 0, stream>>>(eidx, eattr, row_start, fill, epack);
    k_init<<<NNODES / 16, 256, 0, stream>>>(x, embBlock, w1T, b2e_b1, w2T, b2e_b2, hF);
    k_p0<<<NB, 64, 0, stream>>>(hF, bondTP, P0);

    for (int step = 0; step < NSTEPS; ++step) {
        const float* Pprev = (step & 1) ? P1 : P0;
        float* Pnext = (step & 1) ? P0 : P1;
        int writeP = (step < NSTEPS - 1) ? 1 : 0;
        k_step<<<NB, 512, 0, stream>>>(
            hF, Pprev, Pnext, embBond, rootP, WihP, WhhP, bondTP,
            conv_bias, gru_b_ih, gru_b_hh,
            epack, row_start, inv_deg, writeP);
    }

    k_stem<<<NSTEMS / 16, 512, 0, stream>>>(hF, sni, stypes, embStem,
                                            s1P, s2p_b1, s2P, s2p_b2, s3P, s2p_b3, out_f);
    k_gpred<<<NGRAPHS, 128, 0, stream>>>(hF, batch, g1T, g2p_b1, g2p_w2, g2p_b2, out_f);
}

// Round 6
// 275.192 us; speedup vs baseline: 5.6640x; 1.1745x over previous
//
#include <hip/hip_runtime.h>
#include <math.h>

#define D 128
#define NNODES 8192
#define NEDGES 16384
#define NSTEMS 4096
#define NGRAPHS 256
#define NSTEPS 12
#define OPS 105
#define SLOPE 0.01f
#define MT 32              // nodes per step-block
#define NB (NNODES / MT)   // 256 blocks -> 1 block/CU
#define LDA 136            // padded halfs per LDS row (h/m tiles)
#define LDA2 264           // padded halfs per LDS row (stem cat tile)
#define LDQ 40             // padded halfs per Qh row
#define EMAX 512           // per-block edge cap for the LDS fast path

typedef _Float16 half_t;
typedef __attribute__((ext_vector_type(8))) _Float16 f16x8;
typedef __attribute__((ext_vector_type(4))) float f32x4;

__device__ __forceinline__ float leaky(float x) { return x > 0.f ? x : SLOPE * x; }
__device__ __forceinline__ float fast_sigmoid(float x) {
    return __builtin_amdgcn_rcpf(1.f + __expf(-x));
}
__device__ __forceinline__ float fast_tanh(float x) {
    float e = __expf(2.f * x);
    return 1.f - 2.f * __builtin_amdgcn_rcpf(e + 1.f);
}

// ---------------- setup: pack weights + transpose g1 + zero scratch ----------------
// B-frag 16x16x32: lane L supplies B[k = kt*32 + (L>>4)*8 + j][n = nt*16 + (L&15)], j=0..7.
// idx = ((nt*KT + kt)*64 + L)*8 + j
__global__ void k_setup(
    const float* __restrict__ root, const float* __restrict__ wih,
    const float* __restrict__ whh, const float* __restrict__ bond,
    const float* __restrict__ sw1, const float* __restrict__ sw2,
    const float* __restrict__ sw3, const float* __restrict__ bw1,
    const float* __restrict__ bw2, const float* __restrict__ gw1,
    half_t* __restrict__ rootP, half_t* __restrict__ WihP,
    half_t* __restrict__ WhhP, half_t* __restrict__ bondTP,
    half_t* __restrict__ s1P, half_t* __restrict__ s2P, half_t* __restrict__ s3P,
    half_t* __restrict__ w1P, half_t* __restrict__ w2P, half_t* __restrict__ bondQP,
    float* __restrict__ g1T, int* __restrict__ zeroi) {
    int idx = blockIdx.x * 256 + threadIdx.x;
    int which = blockIdx.y;
    if (which == 10) {   // g1T transpose
        if (idx < 128 * 128) {
            int r = idx >> 7, c = idx & 127;
            g1T[c * 128 + r] = gw1[idx];
        }
        return;
    }
    if (which == 11) {   // zero deg+fill
        if (idx < 2 * NNODES) zeroi[idx] = 0;
        return;
    }
    int KT = (which == 4) ? 8 : (which == 9) ? 1 : 4;
    int NT = (which == 1 || which == 2) ? 24 : (which == 3) ? 2 : (which == 6) ? 7 : 8;
    if (idx >= NT * KT * 512) return;
    int j = idx & 7;
    int L = (idx >> 3) & 63;
    int t = idx >> 9;
    int kt = t % KT, nt = t / KT;
    int k = kt * 32 + (L >> 4) * 8 + j;
    int n = nt * 16 + (L & 15);
    switch (which) {
        case 0: rootP[idx] = (half_t)root[k * D + n]; break;
        case 1: WihP[idx] = (half_t)wih[n * D + k]; break;
        case 2: WhhP[idx] = (half_t)whh[n * D + k]; break;
        case 3: bondTP[idx] = (half_t)bond[n * D + k]; break;
        case 4: s1P[idx] = (half_t)sw1[n * 256 + k]; break;
        case 5: s2P[idx] = (half_t)sw2[n * 128 + k]; break;
        case 6: s3P[idx] = (n < OPS) ? (half_t)sw3[n * 128 + k] : (half_t)0.f; break;
        case 7: w1P[idx] = (half_t)bw1[n * D + k]; break;
        case 8: w2P[idx] = (half_t)bw2[n * D + k]; break;
        case 9: bondQP[idx] = (half_t)bond[k * D + n]; break;   // Q@bond: B[k=t][n]
    }
}

__global__ void k_deg(const int* __restrict__ eidx, int* __restrict__ deg) {
    int e = blockIdx.x * 256 + threadIdx.x;
    if (e < NEDGES) atomicAdd(&deg[eidx[NEDGES + e]], 1);
}

__global__ void k_scan(const int* __restrict__ deg, int* __restrict__ row_start,
                       float* __restrict__ inv_deg) {
    __shared__ int sums[256];
    int t = threadIdx.x;
    int base = t * 32;
    int s = 0;
    for (int k = 0; k < 32; ++k) s += deg[base + k];
    sums[t] = s;
    __syncthreads();
    for (int off = 1; off < 256; off <<= 1) {
        int v = sums[t];
        int u = (t >= off) ? sums[t - off] : 0;
        __syncthreads();
        sums[t] = v + u;
        __syncthreads();
    }
    int run = sums[t] - s;
    for (int k = 0; k < 32; ++k) {
        int d = deg[base + k];
        row_start[base + k] = run;
        run += d;
        inv_deg[base + k] = (d > 0) ? (1.0f / (float)d) : 0.0f;
    }
    if (t == 255) row_start[NNODES] = run;
}

// CSR-ordered packed edges: epack[pos] = {src, a0, a1, 0}
__global__ void k_scatter(const int* __restrict__ eidx, const int* __restrict__ eattr,
                          const int* __restrict__ row_start,
                          int* __restrict__ fill, int4* __restrict__ epack) {
    int e = blockIdx.x * 256 + threadIdx.x;
    if (e < NEDGES) {
        int d = eidx[NEDGES + e];
        int pos = row_start[d] + atomicAdd(&fill[d], 1);
        int2 aa = *(const int2*)(eattr + 2 * e);
        epack[pos] = make_int4(eidx[e], aa.x, aa.y, 0);
    }
}

// ---------------- init (MFMA) + fused P0: h0 = act(emb@W1^T+b1)@W2^T+b2 ----------------
// 256 blocks x 512 threads; 32 nodes/block; wave w owns cols [16w,16w+16).
__global__ __launch_bounds__(512, 2) void k_init(
    const int* __restrict__ x, const float* __restrict__ embBlock,
    const half_t* __restrict__ w1P, const float* __restrict__ b1,
    const half_t* __restrict__ w2P, const float* __restrict__ b2,
    const half_t* __restrict__ bondTP,
    float* __restrict__ hF, float* __restrict__ P0) {
    __shared__ __align__(16) half_t Ae[MT * LDA];
    __shared__ __align__(16) half_t T1[MT * LDA];
    const int tid = threadIdx.x;
    const int w = tid >> 6;
    const int lane = tid & 63;
    const int quad = lane >> 4;
    const int l16 = lane & 15;
    const int n0 = blockIdx.x * MT;
    const int c = w * 16 + l16;

    {
        int row = tid >> 4;
        int col = (tid & 15) * 8;
        const float* src = embBlock + (size_t)x[n0 + row] * D + col;
        float4 v0 = ((const float4*)src)[0];
        float4 v1 = ((const float4*)src)[1];
        f16x8 hv;
        hv[0] = (half_t)v0.x; hv[1] = (half_t)v0.y; hv[2] = (half_t)v0.z; hv[3] = (half_t)v0.w;
        hv[4] = (half_t)v1.x; hv[5] = (half_t)v1.y; hv[6] = (half_t)v1.z; hv[7] = (half_t)v1.w;
        *(f16x8*)&Ae[row * LDA + col] = hv;
    }
    __syncthreads();

    // L1
    {
        f32x4 acc[2] = {{0.f, 0.f, 0.f, 0.f}, {0.f, 0.f, 0.f, 0.f}};
#pragma unroll
        for (int kt = 0; kt < 4; ++kt) {
            f16x8 b = *(const f16x8*)(w1P + (size_t)((w * 4 + kt) * 64 + lane) * 8);
            f16x8 a0 = *(const f16x8*)&Ae[(0 + l16) * LDA + kt * 32 + quad * 8];
            f16x8 a1 = *(const f16x8*)&Ae[(16 + l16) * LDA + kt * 32 + quad * 8];
            acc[0] = __builtin_amdgcn_mfma_f32_16x16x32_f16(a0, b, acc[0], 0, 0, 0);
            acc[1] = __builtin_amdgcn_mfma_f32_16x16x32_f16(a1, b, acc[1], 0, 0, 0);
        }
        float bb = b1[c];
#pragma unroll
        for (int mt = 0; mt < 2; ++mt)
#pragma unroll
            for (int r = 0; r < 4; ++r)
                T1[(mt * 16 + quad * 4 + r) * LDA + c] = (half_t)leaky(acc[mt][r] + bb);
    }
    __syncthreads();

    // L2 (no activation), write hF + reuse Ae as h-tile for P0
    {
        f32x4 acc[2] = {{0.f, 0.f, 0.f, 0.f}, {0.f, 0.f, 0.f, 0.f}};
#pragma unroll
        for (int kt = 0; kt < 4; ++kt) {
            f16x8 b = *(const f16x8*)(w2P + (size_t)((w * 4 + kt) * 64 + lane) * 8);
            f16x8 a0 = *(const f16x8*)&T1[(0 + l16) * LDA + kt * 32 + quad * 8];
            f16x8 a1 = *(const f16x8*)&T1[(16 + l16) * LDA + kt * 32 + quad * 8];
            acc[0] = __builtin_amdgcn_mfma_f32_16x16x32_f16(a0, b, acc[0], 0, 0, 0);
            acc[1] = __builtin_amdgcn_mfma_f32_16x16x32_f16(a1, b, acc[1], 0, 0, 0);
        }
        float bb = b2[c];
#pragma unroll
        for (int mt = 0; mt < 2; ++mt)
#pragma unroll
            for (int r = 0; r < 4; ++r) {
                int row = mt * 16 + quad * 4 + r;
                float h = acc[mt][r] + bb;
                hF[(size_t)(n0 + row) * D + c] = h;
                Ae[row * LDA + c] = (half_t)h;
            }
    }
    __syncthreads();

    if (w < 4) {   // P0 = h0 @ bond^T
        int mt = w >> 1, nt = w & 1;
        f32x4 acc = {0.f, 0.f, 0.f, 0.f};
#pragma unroll
        for (int kt = 0; kt < 4; ++kt) {
            f16x8 b = *(const f16x8*)(bondTP + (size_t)((nt * 4 + kt) * 64 + lane) * 8);
            f16x8 a = *(const f16x8*)&Ae[(mt * 16 + l16) * LDA + kt * 32 + quad * 8];
            acc = __builtin_amdgcn_mfma_f32_16x16x32_f16(a, b, acc, 0, 0, 0);
        }
#pragma unroll
        for (int r = 0; r < 4; ++r)
            P0[(size_t)(n0 + mt * 16 + quad * 4 + r) * 32 + nt * 16 + l16] = acc[r];
    }
}

// ---------------- one conv+GRU step ----------------
// 256 blocks x 512 threads; block owns 32 nodes; wave w owns cols [16w,16w+16).
// Edge path: depth-1 gather -> Q matrix (32x32) in LDS -> ONE agg MFMA per wave.
__global__ __launch_bounds__(512, 2) void k_step(
    float* __restrict__ hF,
    const float* __restrict__ Pprev, float* __restrict__ Pnext,
    const half_t* __restrict__ rootP, const half_t* __restrict__ WihP,
    const half_t* __restrict__ WhhP, const half_t* __restrict__ bondTP,
    const half_t* __restrict__ bondQP,
    const float* __restrict__ cbias, const float* __restrict__ bih,
    const float* __restrict__ bhh,
    const int4* __restrict__ epack,
    const int* __restrict__ row_start, const float* __restrict__ inv_deg, int writeP) {
    __shared__ __align__(16) half_t As[MT * LDA];
    __shared__ __align__(16) half_t Am[MT * LDA];
    __shared__ __align__(16) half_t Qh[MT * LDQ];
    __shared__ float Q[MT * 32];
    __shared__ float ws[EMAX];
    __shared__ int ea1[EMAX];

    const int tid = threadIdx.x;
    const int w = tid >> 6;
    const int lane = tid & 63;
    const int quad = lane >> 4;
    const int l16 = lane & 15;
    const int n0 = blockIdx.x * MT;
    const int c = w * 16 + l16;

    // --- phase A: stage h->As, zero Q, old-h loads, edge gathers ---
    {
        int row = tid >> 4;
        int col = (tid & 15) * 8;
        const float* src = hF + (size_t)(n0 + row) * D + col;
        float4 v0 = ((const float4*)src)[0];
        float4 v1 = ((const float4*)src)[1];
        f16x8 hv;
        hv[0] = (half_t)v0.x; hv[1] = (half_t)v0.y; hv[2] = (half_t)v0.z; hv[3] = (half_t)v0.w;
        hv[4] = (half_t)v1.x; hv[5] = (half_t)v1.y; hv[6] = (half_t)v1.z; hv[7] = (half_t)v1.w;
        *(f16x8*)&As[row * LDA + col] = hv;
    }
    Q[tid] = 0.f;
    Q[tid + 512] = 0.f;
    float hold[2][4];
#pragma unroll
    for (int mt = 0; mt < 2; ++mt)
#pragma unroll
        for (int r = 0; r < 4; ++r)
            hold[mt][r] = hF[(size_t)(n0 + mt * 16 + quad * 4 + r) * D + c];
    const int p0 = row_start[n0];
    const int p1 = row_start[n0 + MT];
    const int ne = p1 - p0;
    const int nec = ne < EMAX ? ne : EMAX;
    int4 ep;
    float wv = 0.f;
    const bool have = (tid < nec);
    if (have) {
        ep = epack[p0 + tid];
        wv = Pprev[(size_t)ep.x * 32 + ep.y];
    }
    const float cb = cbias[c];
    const float bi0 = bih[c], bi1 = bih[D + c], bi2 = bih[2 * D + c];
    const float bh0 = bhh[c], bh1 = bhh[D + c], bh2 = bhh[2 * D + c];
    __syncthreads();

    // --- phase B: conv + gh MFMAs; prefetch gi/agg B-frags ---
    f32x4 convAcc[2] = {{0.f, 0.f, 0.f, 0.f}, {0.f, 0.f, 0.f, 0.f}};
#pragma unroll
    for (int kt = 0; kt < 4; ++kt) {
        f16x8 b = *(const f16x8*)(rootP + (size_t)((w * 4 + kt) * 64 + lane) * 8);
        f16x8 a0 = *(const f16x8*)&As[(0 + l16) * LDA + kt * 32 + quad * 8];
        f16x8 a1 = *(const f16x8*)&As[(16 + l16) * LDA + kt * 32 + quad * 8];
        convAcc[0] = __builtin_amdgcn_mfma_f32_16x16x32_f16(a0, b, convAcc[0], 0, 0, 0);
        convAcc[1] = __builtin_amdgcn_mfma_f32_16x16x32_f16(a1, b, convAcc[1], 0, 0, 0);
    }
    f32x4 ghA[2][3];
#pragma unroll
    for (int mt = 0; mt < 2; ++mt)
#pragma unroll
        for (int g = 0; g < 3; ++g) ghA[mt][g] = f32x4{0.f, 0.f, 0.f, 0.f};
#pragma unroll
    for (int kt = 0; kt < 4; ++kt) {
        f16x8 a0 = *(const f16x8*)&As[(0 + l16) * LDA + kt * 32 + quad * 8];
        f16x8 a1 = *(const f16x8*)&As[(16 + l16) * LDA + kt * 32 + quad * 8];
#pragma unroll
        for (int g = 0; g < 3; ++g) {
            f16x8 b = *(const f16x8*)(WhhP + (size_t)(((g * 8 + w) * 4 + kt) * 64 + lane) * 8);
            ghA[0][g] = __builtin_amdgcn_mfma_f32_16x16x32_f16(a0, b, ghA[0][g], 0, 0, 0);
            ghA[1][g] = __builtin_amdgcn_mfma_f32_16x16x32_f16(a1, b, ghA[1][g], 0, 0, 0);
        }
    }
    // prefetch B-frags used after later syncs
    f16x8 giB[12];
#pragma unroll
    for (int kt = 0; kt < 4; ++kt)
#pragma unroll
        for (int g = 0; g < 3; ++g)
            giB[g * 4 + kt] = *(const f16x8*)(WihP + (size_t)(((g * 8 + w) * 4 + kt) * 64 + lane) * 8);
    f16x8 aggB = *(const f16x8*)(bondQP + (size_t)(w * 64 + lane) * 8);
    if (have) {
        ws[tid] = wv;
        ea1[tid] = ep.z;
    }
    __syncthreads();

    // --- phase C: Q build (one lane per node), convert to fp16 ---
    if (tid < MT) {
        int node = n0 + tid;
        float idg = inv_deg[node];
        int q0 = row_start[node], q1 = row_start[node + 1];
        for (int p = q0; p < q1; ++p) {
            int rel = p - p0;
            if (rel < EMAX) {
                Q[tid * 32 + ea1[rel]] += ws[rel] * idg;
            } else {
                int4 e2 = epack[p];
                Q[tid * 32 + e2.z] += Pprev[(size_t)e2.x * 32 + e2.y] * idg;
            }
        }
#pragma unroll
        for (int k = 0; k < 32; ++k) Qh[tid * LDQ + k] = (half_t)Q[tid * 32 + k];
    }
    __syncthreads();

    // --- phase D: agg MFMA + m -> Am ---
    {
#pragma unroll
        for (int mt = 0; mt < 2; ++mt) {
            f32x4 acc = {0.f, 0.f, 0.f, 0.f};
            f16x8 a = *(const f16x8*)&Qh[(mt * 16 + l16) * LDQ + quad * 8];
            acc = __builtin_amdgcn_mfma_f32_16x16x32_f16(a, aggB, acc, 0, 0, 0);
#pragma unroll
            for (int r = 0; r < 4; ++r) {
                float m = convAcc[mt][r] + cb + acc[r];
                Am[(mt * 16 + quad * 4 + r) * LDA + c] = (half_t)leaky(m);
            }
        }
    }
    __syncthreads();

    // --- phase E: gi MFMAs + GRU combine ---
    f32x4 giA[2][3];
#pragma unroll
    for (int mt = 0; mt < 2; ++mt)
#pragma unroll
        for (int g = 0; g < 3; ++g) giA[mt][g] = f32x4{0.f, 0.f, 0.f, 0.f};
#pragma unroll
    for (int kt = 0; kt < 4; ++kt) {
        f16x8 a0 = *(const f16x8*)&Am[(0 + l16) * LDA + kt * 32 + quad * 8];
        f16x8 a1 = *(const f16x8*)&Am[(16 + l16) * LDA + kt * 32 + quad * 8];
#pragma unroll
        for (int g = 0; g < 3; ++g) {
            giA[0][g] = __builtin_amdgcn_mfma_f32_16x16x32_f16(a0, giB[g * 4 + kt], giA[0][g], 0, 0, 0);
            giA[1][g] = __builtin_amdgcn_mfma_f32_16x16x32_f16(a1, giB[g * 4 + kt], giA[1][g], 0, 0, 0);
        }
    }
#pragma unroll
    for (int mt = 0; mt < 2; ++mt) {
#pragma unroll
        for (int r = 0; r < 4; ++r) {
            int row = mt * 16 + quad * 4 + r;
            float rg = fast_sigmoid(giA[mt][0][r] + bi0 + ghA[mt][0][r] + bh0);
            float z = fast_sigmoid(giA[mt][1][r] + bi1 + ghA[mt][1][r] + bh1);
            float nn = fast_tanh(giA[mt][2][r] + bi2 + rg * (ghA[mt][2][r] + bh2));
            float hnew = (1.f - z) * nn + z * hold[mt][r];
            hF[(size_t)(n0 + row) * D + c] = hnew;
            As[row * LDA + c] = (half_t)hnew;
        }
    }

    if (writeP) {
        __syncthreads();
        if (w < 4) {
            int mt = w >> 1, nt = w & 1;
            f32x4 acc = {0.f, 0.f, 0.f, 0.f};
#pragma unroll
            for (int kt = 0; kt < 4; ++kt) {
                f16x8 b = *(const f16x8*)(bondTP + (size_t)((nt * 4 + kt) * 64 + lane) * 8);
                f16x8 a = *(const f16x8*)&As[(mt * 16 + l16) * LDA + kt * 32 + quad * 8];
                acc = __builtin_amdgcn_mfma_f32_16x16x32_f16(a, b, acc, 0, 0, 0);
            }
#pragma unroll
            for (int r = 0; r < 4; ++r)
                Pnext[(size_t)(n0 + mt * 16 + quad * 4 + r) * 32 + nt * 16 + l16] = acc[r];
        }
    }
}

// ---------------- stem head (MFMA) + fused gpred ----------------
__device__ __forceinline__ int lower_bound_dev(const int* a, int n, int v) {
    int lo = 0, hi = n;
    while (lo < hi) {
        int m = (lo + hi) >> 1;
        if (a[m] < v) lo = m + 1;
        else hi = m;
    }
    return lo;
}

__global__ __launch_bounds__(512) void k_heads(
    const float* __restrict__ hF, const int* __restrict__ sni, const int* __restrict__ stypes,
    const float* __restrict__ embStem,
    const half_t* __restrict__ s1P, const float* __restrict__ b1,
    const half_t* __restrict__ s2P, const float* __restrict__ b2,
    const half_t* __restrict__ s3P, const float* __restrict__ b3,
    const int* __restrict__ batch,
    const float* __restrict__ g1T, const float* __restrict__ gb1,
    const float* __restrict__ gw2, const float* __restrict__ gb2,
    float* __restrict__ dout) {
    __shared__ __align__(16) half_t cat[16 * LDA2];
    __shared__ __align__(16) half_t t1[16 * LDA];
    __shared__ __align__(16) half_t t2[16 * LDA];
    const int tid = threadIdx.x;
    if (blockIdx.x >= 256) {
        // ---- gpred path ----
        int g = blockIdx.x - 256;
        if (tid >= 128) return;
        __shared__ float mean_s[D];
        __shared__ float red[D];
        int j = tid;
        int lo = lower_bound_dev(batch, NNODES, g);
        int hi = lower_bound_dev(batch, NNODES, g + 1);
        float sum = 0.f;
        for (int n = lo; n < hi; ++n) sum += hF[(size_t)n * D + j];
        float denom = (hi > lo) ? (float)(hi - lo) : 1.0f;
        mean_s[j] = sum / denom;
        __syncthreads();
        float a = gb1[j];
        for (int i = 0; i < D; ++i) a += mean_s[i] * g1T[i * D + j];
        a = leaky(a);
        red[j] = a * gw2[j];
        __syncthreads();
        for (int off = 64; off > 0; off >>= 1) {
            if (j < off) red[j] += red[j + off];
            __syncthreads();
        }
        if (j == 0) dout[NSTEMS * OPS + g] = red[0] + gb2[0];
        return;
    }
    // ---- stem path ----
    const int w = tid >> 6;
    const int lane = tid & 63;
    const int quad = lane >> 4;
    const int l16 = lane & 15;
    const int s0 = blockIdx.x * 16;
    const int c = w * 16 + l16;

    {
        int row = tid >> 5;
        int col = (tid & 31) * 8;
        const float* src;
        if (col < D) src = hF + (size_t)sni[s0 + row] * D + col;
        else src = embStem + (size_t)stypes[s0 + row] * D + (col - D);
        float4 v0 = ((const float4*)src)[0];
        float4 v1 = ((const float4*)src)[1];
        f16x8 hv;
        hv[0] = (half_t)v0.x; hv[1] = (half_t)v0.y; hv[2] = (half_t)v0.z; hv[3] = (half_t)v0.w;
        hv[4] = (half_t)v1.x; hv[5] = (half_t)v1.y; hv[6] = (half_t)v1.z; hv[7] = (half_t)v1.w;
        *(f16x8*)&cat[row * LDA2 + col] = hv;
    }
    __syncthreads();

    {
        f32x4 acc = {0.f, 0.f, 0.f, 0.f};
#pragma unroll
        for (int kt = 0; kt < 8; ++kt) {
            f16x8 b = *(const f16x8*)(s1P + (size_t)((w * 8 + kt) * 64 + lane) * 8);
            f16x8 a = *(const f16x8*)&cat[l16 * LDA2 + kt * 32 + quad * 8];
            acc = __builtin_amdgcn_mfma_f32_16x16x32_f16(a, b, acc, 0, 0, 0);
        }
        float bb = b1[c];
#pragma unroll
        for (int r = 0; r < 4; ++r)
            t1[(quad * 4 + r) * LDA + c] = (half_t)leaky(acc[r] + bb);
    }
    __syncthreads();
    {
        f32x4 acc = {0.f, 0.f, 0.f, 0.f};
#pragma unroll
        for (int kt = 0; kt < 4; ++kt) {
            f16x8 b = *(const f16x8*)(s2P + (size_t)((w * 4 + kt) * 64 + lane) * 8);
            f16x8 a = *(const f16x8*)&t1[l16 * LDA + kt * 32 + quad * 8];
            acc = __builtin_amdgcn_mfma_f32_16x16x32_f16(a, b, acc, 0, 0, 0);
        }
        float bb = b2[c];
#pragma unroll
        for (int r = 0; r < 4; ++r)
            t2[(quad * 4 + r) * LDA + c] = (half_t)leaky(acc[r] + bb);
    }
    __syncthreads();
    if (w < 7) {
        f32x4 acc = {0.f, 0.f, 0.f, 0.f};
#pragma unroll
        for (int kt = 0; kt < 4; ++kt) {
            f16x8 b = *(const f16x8*)(s3P + (size_t)((w * 4 + kt) * 64 + lane) * 8);
            f16x8 a = *(const f16x8*)&t2[l16 * LDA + kt * 32 + quad * 8];
            acc = __builtin_amdgcn_mfma_f32_16x16x32_f16(a, b, acc, 0, 0, 0);
        }
        int j = w * 16 + l16;
        if (j < OPS) {
            float bb = b3[j];
#pragma unroll
            for (int r = 0; r < 4; ++r)
                dout[(size_t)(s0 + quad * 4 + r) * OPS + j] = acc[r] + bb;
        }
    }
}

// ---------------- launch ----------------
extern "C" void kernel_launch(void* const* d_in, const int* in_sizes, int n_in,
                              void* d_out, int out_size, void* d_ws, size_t ws_size,
                              hipStream_t stream) {
    const int* x = (const int*)d_in[0];
    const int* stypes = (const int*)d_in[1];
    const int* eattr = (const int*)d_in[2];
    const int* eidx = (const int*)d_in[3];
    const int* sni = (const int*)d_in[4];
    const int* batch = (const int*)d_in[5];
    const float* embBlock = (const float*)d_in[6];
    const float* embStem = (const float*)d_in[7];
    const float* embBond = (const float*)d_in[8];
    const float* b2e_w1 = (const float*)d_in[9];
    const float* b2e_b1 = (const float*)d_in[10];
    const float* b2e_w2 = (const float*)d_in[11];
    const float* b2e_b2 = (const float*)d_in[12];
    const float* conv_root = (const float*)d_in[13];
    const float* conv_bias = (const float*)d_in[14];
    const float* gru_w_ih = (const float*)d_in[15];
    const float* gru_w_hh = (const float*)d_in[16];
    const float* gru_b_ih = (const float*)d_in[17];
    const float* gru_b_hh = (const float*)d_in[18];
    const float* s2p_w1 = (const float*)d_in[19];
    const float* s2p_b1 = (const float*)d_in[20];
    const float* s2p_w2 = (const float*)d_in[21];
    const float* s2p_b2 = (const float*)d_in[22];
    const float* s2p_w3 = (const float*)d_in[23];
    const float* s2p_b3 = (const float*)d_in[24];
    const float* g2p_w1 = (const float*)d_in[25];
    const float* g2p_b1 = (const float*)d_in[26];
    const float* g2p_w2 = (const float*)d_in[27];
    const float* g2p_b2 = (const float*)d_in[28];
    float* out_f = (float*)d_out;

    float* W = (float*)d_ws;
    size_t off = 0;
    auto alloc = [&](size_t words) {
        size_t o = off;
        off += (words + 3) & ~(size_t)3;
        return o;
    };
    float* hF = W + alloc(NNODES * D);
    float* P0 = W + alloc(NNODES * 32);
    float* P1 = W + alloc(NNODES * 32);
    half_t* rootP = (half_t*)(W + alloc(16384 / 2));
    half_t* WihP = (half_t*)(W + alloc(49152 / 2));
    half_t* WhhP = (half_t*)(W + alloc(49152 / 2));
    half_t* bondTP = (half_t*)(W + alloc(4096 / 2));
    half_t* s1P = (half_t*)(W + alloc(32768 / 2));
    half_t* s2P = (half_t*)(W + alloc(16384 / 2));
    half_t* s3P = (half_t*)(W + alloc(14336 / 2));
    half_t* w1P = (half_t*)(W + alloc(16384 / 2));
    half_t* w2P = (half_t*)(W + alloc(16384 / 2));
    half_t* bondQP = (half_t*)(W + alloc(4096 / 2));
    float* g1T = W + alloc(128 * 128);
    int* row_start = (int*)(W + alloc(NNODES + 1));
    int4* epack = (int4*)(W + alloc(NEDGES * 4));
    float* inv_deg = W + alloc(NNODES);
    float* zbase = W + alloc(2 * NNODES);   // deg + fill
    int* deg = (int*)zbase;
    int* fill = deg + NNODES;

    k_setup<<<dim3(192, 12), 256, 0, stream>>>(
        conv_root, gru_w_ih, gru_w_hh, embBond, s2p_w1, s2p_w2, s2p_w3,
        b2e_w1, b2e_w2, g2p_w1,
        rootP, WihP, WhhP, bondTP, s1P, s2P, s3P, w1P, w2P, bondQP,
        g1T, (int*)zbase);
    k_deg<<<(NEDGES + 255) / 256, 256, 0, stream>>>(eidx, deg);
    k_scan<<<1, 256, 0, stream>>>(deg, row_start, inv_deg);
    k_scatter<<<(NEDGES + 255) / 256, 256, 0, stream>>>(eidx, eattr, row_start, fill, epack);
    k_init<<<NNODES / MT, 512, 0, stream>>>(x, embBlock, w1P, b2e_b1, w2P, b2e_b2,
                                            bondTP, hF, P0);

    for (int step = 0; step < NSTEPS; ++step) {
        const float* Pprev = (step & 1) ? P1 : P0;
        float* Pnext = (step & 1) ? P0 : P1;
        int writeP = (step < NSTEPS - 1) ? 1 : 0;
        k_step<<<NB, 512, 0, stream>>>(
            hF, Pprev, Pnext, rootP, WihP, WhhP, bondTP, bondQP,
            conv_bias, gru_b_ih, gru_b_hh,
            epack, row_start, inv_deg, writeP);
    }

    k_heads<<<NSTEMS / 16 + NGRAPHS, 512, 0, stream>>>(
        hF, sni, stypes, embStem,
        s1P, s2p_b1, s2P, s2p_b2, s3P, s2p_b3,
        batch, g1T, g2p_b1, g2p_w2, g2p_b2, out_f);
}

// Round 7
// 251.696 us; speedup vs baseline: 6.1927x; 1.0933x over previous
//
#include <hip/hip_runtime.h>
#include <math.h>

#define D 128
#define NNODES 8192
#define NEDGES 16384
#define NSTEMS 4096
#define NGRAPHS 256
#define NSTEPS 12
#define OPS 105
#define SLOPE 0.01f
#define MT 32              // nodes per step-block
#define NB (NNODES / MT)   // 256 blocks -> 1 block/CU
#define LDA 136            // padded halfs per LDS row (h/m tiles)
#define LDA2 264           // padded halfs per LDS row (stem cat tile)
#define LDQ 40             // padded halfs per Qh row
#define LDH 132            // padded floats per Hs row

typedef _Float16 half_t;
typedef __attribute__((ext_vector_type(8))) _Float16 f16x8;
typedef __attribute__((ext_vector_type(4))) float f32x4;

__device__ __forceinline__ float leaky(float x) { return x > 0.f ? x : SLOPE * x; }
__device__ __forceinline__ float fast_sigmoid(float x) {
    return __builtin_amdgcn_rcpf(1.f + __expf(-x));
}
__device__ __forceinline__ float fast_tanh(float x) {
    float e = __expf(2.f * x);
    return 1.f - 2.f * __builtin_amdgcn_rcpf(e + 1.f);
}

// ---------------- setup: pack weights + transpose g1 + zero scratch ----------------
// B-frag 16x16x32: lane L supplies B[k = kt*32 + (L>>4)*8 + j][n = nt*16 + (L&15)], j=0..7.
// idx = ((nt*KT + kt)*64 + L)*8 + j
__global__ void k_setup(
    const float* __restrict__ root, const float* __restrict__ wih,
    const float* __restrict__ whh, const float* __restrict__ bond,
    const float* __restrict__ sw1, const float* __restrict__ sw2,
    const float* __restrict__ sw3, const float* __restrict__ bw1,
    const float* __restrict__ bw2, const float* __restrict__ gw1,
    half_t* __restrict__ rootP, half_t* __restrict__ WihP,
    half_t* __restrict__ WhhP, half_t* __restrict__ bondTP,
    half_t* __restrict__ s1P, half_t* __restrict__ s2P, half_t* __restrict__ s3P,
    half_t* __restrict__ w1P, half_t* __restrict__ w2P, half_t* __restrict__ bondQP,
    float* __restrict__ g1T, int* __restrict__ zeroi) {
    int idx = blockIdx.x * 256 + threadIdx.x;
    int which = blockIdx.y;
    if (which == 10) {   // g1T transpose
        if (idx < 128 * 128) {
            int r = idx >> 7, c = idx & 127;
            g1T[c * 128 + r] = gw1[idx];
        }
        return;
    }
    if (which == 11) {   // zero deg+fill
        if (idx < 2 * NNODES) zeroi[idx] = 0;
        return;
    }
    int KT = (which == 4) ? 8 : (which == 9) ? 1 : 4;
    int NT = (which == 1 || which == 2) ? 24 : (which == 3) ? 2 : (which == 6) ? 7 : 8;
    if (idx >= NT * KT * 512) return;
    int j = idx & 7;
    int L = (idx >> 3) & 63;
    int t = idx >> 9;
    int kt = t % KT, nt = t / KT;
    int k = kt * 32 + (L >> 4) * 8 + j;
    int n = nt * 16 + (L & 15);
    switch (which) {
        case 0: rootP[idx] = (half_t)root[k * D + n]; break;
        case 1: WihP[idx] = (half_t)wih[n * D + k]; break;
        case 2: WhhP[idx] = (half_t)whh[n * D + k]; break;
        case 3: bondTP[idx] = (half_t)bond[n * D + k]; break;
        case 4: s1P[idx] = (half_t)sw1[n * 256 + k]; break;
        case 5: s2P[idx] = (half_t)sw2[n * 128 + k]; break;
        case 6: s3P[idx] = (n < OPS) ? (half_t)sw3[n * 128 + k] : (half_t)0.f; break;
        case 7: w1P[idx] = (half_t)bw1[n * D + k]; break;
        case 8: w2P[idx] = (half_t)bw2[n * D + k]; break;
        case 9: bondQP[idx] = (half_t)bond[k * D + n]; break;   // Q@bond: B[k=t][n]
    }
}

__global__ void k_deg(const int* __restrict__ eidx, int* __restrict__ deg) {
    int e = blockIdx.x * 256 + threadIdx.x;
    if (e < NEDGES) atomicAdd(&deg[eidx[NEDGES + e]], 1);
}

__global__ void k_scan(const int* __restrict__ deg, int* __restrict__ row_start,
                       float* __restrict__ inv_deg) {
    __shared__ int sums[256];
    int t = threadIdx.x;
    int base = t * 32;
    int s = 0;
    for (int k = 0; k < 32; ++k) s += deg[base + k];
    sums[t] = s;
    __syncthreads();
    for (int off = 1; off < 256; off <<= 1) {
        int v = sums[t];
        int u = (t >= off) ? sums[t - off] : 0;
        __syncthreads();
        sums[t] = v + u;
        __syncthreads();
    }
    int run = sums[t] - s;
    for (int k = 0; k < 32; ++k) {
        int d = deg[base + k];
        row_start[base + k] = run;
        run += d;
        inv_deg[base + k] = (d > 0) ? (1.0f / (float)d) : 0.0f;
    }
    if (t == 255) row_start[NNODES] = run;
}

// CSR-ordered packed edges: epack[pos] = {src, a0, a1, dst}
__global__ void k_scatter(const int* __restrict__ eidx, const int* __restrict__ eattr,
                          const int* __restrict__ row_start,
                          int* __restrict__ fill, int4* __restrict__ epack) {
    int e = blockIdx.x * 256 + threadIdx.x;
    if (e < NEDGES) {
        int d = eidx[NEDGES + e];
        int pos = row_start[d] + atomicAdd(&fill[d], 1);
        int2 aa = *(const int2*)(eattr + 2 * e);
        epack[pos] = make_int4(eidx[e], aa.x, aa.y, d);
    }
}

// ---------------- init (MFMA) + fused P0 ----------------
__global__ __launch_bounds__(512, 2) void k_init(
    const int* __restrict__ x, const float* __restrict__ embBlock,
    const half_t* __restrict__ w1P, const float* __restrict__ b1,
    const half_t* __restrict__ w2P, const float* __restrict__ b2,
    const half_t* __restrict__ bondTP,
    float* __restrict__ hF, float* __restrict__ P0) {
    __shared__ __align__(16) half_t Ae[MT * LDA];
    __shared__ __align__(16) half_t T1[MT * LDA];
    const int tid = threadIdx.x;
    const int w = tid >> 6;
    const int lane = tid & 63;
    const int quad = lane >> 4;
    const int l16 = lane & 15;
    const int n0 = blockIdx.x * MT;
    const int c = w * 16 + l16;

    {
        int row = tid >> 4;
        int col = (tid & 15) * 8;
        const float* src = embBlock + (size_t)x[n0 + row] * D + col;
        float4 v0 = ((const float4*)src)[0];
        float4 v1 = ((const float4*)src)[1];
        f16x8 hv;
        hv[0] = (half_t)v0.x; hv[1] = (half_t)v0.y; hv[2] = (half_t)v0.z; hv[3] = (half_t)v0.w;
        hv[4] = (half_t)v1.x; hv[5] = (half_t)v1.y; hv[6] = (half_t)v1.z; hv[7] = (half_t)v1.w;
        *(f16x8*)&Ae[row * LDA + col] = hv;
    }
    __syncthreads();

    {
        f32x4 acc[2] = {{0.f, 0.f, 0.f, 0.f}, {0.f, 0.f, 0.f, 0.f}};
#pragma unroll
        for (int kt = 0; kt < 4; ++kt) {
            f16x8 b = *(const f16x8*)(w1P + (size_t)((w * 4 + kt) * 64 + lane) * 8);
            f16x8 a0 = *(const f16x8*)&Ae[(0 + l16) * LDA + kt * 32 + quad * 8];
            f16x8 a1 = *(const f16x8*)&Ae[(16 + l16) * LDA + kt * 32 + quad * 8];
            acc[0] = __builtin_amdgcn_mfma_f32_16x16x32_f16(a0, b, acc[0], 0, 0, 0);
            acc[1] = __builtin_amdgcn_mfma_f32_16x16x32_f16(a1, b, acc[1], 0, 0, 0);
        }
        float bb = b1[c];
#pragma unroll
        for (int mt = 0; mt < 2; ++mt)
#pragma unroll
            for (int r = 0; r < 4; ++r)
                T1[(mt * 16 + quad * 4 + r) * LDA + c] = (half_t)leaky(acc[mt][r] + bb);
    }
    __syncthreads();

    {
        f32x4 acc[2] = {{0.f, 0.f, 0.f, 0.f}, {0.f, 0.f, 0.f, 0.f}};
#pragma unroll
        for (int kt = 0; kt < 4; ++kt) {
            f16x8 b = *(const f16x8*)(w2P + (size_t)((w * 4 + kt) * 64 + lane) * 8);
            f16x8 a0 = *(const f16x8*)&T1[(0 + l16) * LDA + kt * 32 + quad * 8];
            f16x8 a1 = *(const f16x8*)&T1[(16 + l16) * LDA + kt * 32 + quad * 8];
            acc[0] = __builtin_amdgcn_mfma_f32_16x16x32_f16(a0, b, acc[0], 0, 0, 0);
            acc[1] = __builtin_amdgcn_mfma_f32_16x16x32_f16(a1, b, acc[1], 0, 0, 0);
        }
        float bb = b2[c];
#pragma unroll
        for (int mt = 0; mt < 2; ++mt)
#pragma unroll
            for (int r = 0; r < 4; ++r) {
                int row = mt * 16 + quad * 4 + r;
                float h = acc[mt][r] + bb;
                hF[(size_t)(n0 + row) * D + c] = h;
                Ae[row * LDA + c] = (half_t)h;
            }
    }
    __syncthreads();

    if (w < 4) {   // P0 = h0 @ bond^T
        int mt = w >> 1, nt = w & 1;
        f32x4 acc = {0.f, 0.f, 0.f, 0.f};
#pragma unroll
        for (int kt = 0; kt < 4; ++kt) {
            f16x8 b = *(const f16x8*)(bondTP + (size_t)((nt * 4 + kt) * 64 + lane) * 8);
            f16x8 a = *(const f16x8*)&Ae[(mt * 16 + l16) * LDA + kt * 32 + quad * 8];
            acc = __builtin_amdgcn_mfma_f32_16x16x32_f16(a, b, acc, 0, 0, 0);
        }
#pragma unroll
        for (int r = 0; r < 4; ++r)
            P0[(size_t)(n0 + mt * 16 + quad * 4 + r) * 32 + nt * 16 + l16] = acc[r];
    }
}

// ---------------- one conv+GRU step ----------------
// 256 blocks x 512 threads; block owns 32 nodes; wave w owns cols [16w,16w+16).
// Phase A issues EVERYTHING: h stage, edge gathers, root/gh/agg B-frag prefetch.
// Q built by parallel LDS atomics overlapped with phase-B MFMAs.
__global__ __launch_bounds__(512, 2) void k_step(
    float* __restrict__ hF,
    const float* __restrict__ Pprev, float* __restrict__ Pnext,
    const half_t* __restrict__ rootP, const half_t* __restrict__ WihP,
    const half_t* __restrict__ WhhP, const half_t* __restrict__ bondTP,
    const half_t* __restrict__ bondQP,
    const float* __restrict__ cbias, const float* __restrict__ bih,
    const float* __restrict__ bhh,
    const int4* __restrict__ epack,
    const int* __restrict__ row_start, const float* __restrict__ inv_deg, int writeP) {
    __shared__ __align__(16) half_t As[MT * LDA];
    __shared__ __align__(16) half_t Am[MT * LDA];
    __shared__ __align__(16) float Hs[MT * LDH];
    __shared__ __align__(16) half_t Qh[MT * LDQ];
    __shared__ float Q[MT * 32];

    const int tid = threadIdx.x;
    const int w = tid >> 6;
    const int lane = tid & 63;
    const int quad = lane >> 4;
    const int l16 = lane & 15;
    const int n0 = blockIdx.x * MT;
    const int c = w * 16 + l16;

    // --- phase A: issue all loads ---
    {
        int row = tid >> 4;
        int col = (tid & 15) * 8;
        const float* src = hF + (size_t)(n0 + row) * D + col;
        float4 v0 = ((const float4*)src)[0];
        float4 v1 = ((const float4*)src)[1];
        f16x8 hv;
        hv[0] = (half_t)v0.x; hv[1] = (half_t)v0.y; hv[2] = (half_t)v0.z; hv[3] = (half_t)v0.w;
        hv[4] = (half_t)v1.x; hv[5] = (half_t)v1.y; hv[6] = (half_t)v1.z; hv[7] = (half_t)v1.w;
        *(f16x8*)&As[row * LDA + col] = hv;
        *(float4*)&Hs[row * LDH + col] = v0;
        *(float4*)&Hs[row * LDH + col + 4] = v1;
    }
    Q[tid] = 0.f;
    Q[tid + 512] = 0.f;
    const int p0 = row_start[n0];
    const int p1 = row_start[n0 + MT];
    int4 ep;
    float wv = 0.f, idg = 0.f;
    const int pme = p0 + tid;
    const bool have = (pme < p1);
    if (have) {
        ep = epack[pme];
        wv = Pprev[(size_t)ep.x * 32 + ep.y];
        idg = inv_deg[ep.w];
    }
    // prefetch B-fragments: conv root (4), gh (12), agg (1)
    f16x8 rootB[4], ghB[12], aggB;
#pragma unroll
    for (int kt = 0; kt < 4; ++kt)
        rootB[kt] = *(const f16x8*)(rootP + (size_t)((w * 4 + kt) * 64 + lane) * 8);
#pragma unroll
    for (int kt = 0; kt < 4; ++kt)
#pragma unroll
        for (int g = 0; g < 3; ++g)
            ghB[g * 4 + kt] = *(const f16x8*)(WhhP + (size_t)(((g * 8 + w) * 4 + kt) * 64 + lane) * 8);
    aggB = *(const f16x8*)(bondQP + (size_t)(w * 64 + lane) * 8);
    const float cb = cbias[c];
    const float bi0 = bih[c], bi1 = bih[D + c], bi2 = bih[2 * D + c];
    const float bh0 = bhh[c], bh1 = bhh[D + c], bh2 = bhh[2 * D + c];
    __syncthreads();

    // --- phase B: conv + gh MFMAs; Q atomics overlap ---
    f32x4 convAcc[2] = {{0.f, 0.f, 0.f, 0.f}, {0.f, 0.f, 0.f, 0.f}};
#pragma unroll
    for (int kt = 0; kt < 4; ++kt) {
        f16x8 a0 = *(const f16x8*)&As[(0 + l16) * LDA + kt * 32 + quad * 8];
        f16x8 a1 = *(const f16x8*)&As[(16 + l16) * LDA + kt * 32 + quad * 8];
        convAcc[0] = __builtin_amdgcn_mfma_f32_16x16x32_f16(a0, rootB[kt], convAcc[0], 0, 0, 0);
        convAcc[1] = __builtin_amdgcn_mfma_f32_16x16x32_f16(a1, rootB[kt], convAcc[1], 0, 0, 0);
    }
    if (have) atomicAdd(&Q[(ep.w - n0) * 32 + ep.z], wv * idg);
    for (int p2 = pme + 512; p2 < p1; p2 += 512) {   // overflow (rare)
        int4 e2 = epack[p2];
        atomicAdd(&Q[(e2.w - n0) * 32 + e2.z], Pprev[(size_t)e2.x * 32 + e2.y] * inv_deg[e2.w]);
    }
    f32x4 ghA[2][3];
#pragma unroll
    for (int mt = 0; mt < 2; ++mt)
#pragma unroll
        for (int g = 0; g < 3; ++g) ghA[mt][g] = f32x4{0.f, 0.f, 0.f, 0.f};
#pragma unroll
    for (int kt = 0; kt < 4; ++kt) {
        f16x8 a0 = *(const f16x8*)&As[(0 + l16) * LDA + kt * 32 + quad * 8];
        f16x8 a1 = *(const f16x8*)&As[(16 + l16) * LDA + kt * 32 + quad * 8];
#pragma unroll
        for (int g = 0; g < 3; ++g) {
            ghA[0][g] = __builtin_amdgcn_mfma_f32_16x16x32_f16(a0, ghB[g * 4 + kt], ghA[0][g], 0, 0, 0);
            ghA[1][g] = __builtin_amdgcn_mfma_f32_16x16x32_f16(a1, ghB[g * 4 + kt], ghA[1][g], 0, 0, 0);
        }
    }
    __syncthreads();   // Q complete

    // --- load gi B-frags (covered by convert/agg phases) ---
    f16x8 giB[12];
#pragma unroll
    for (int kt = 0; kt < 4; ++kt)
#pragma unroll
        for (int g = 0; g < 3; ++g)
            giB[g * 4 + kt] = *(const f16x8*)(WihP + (size_t)(((g * 8 + w) * 4 + kt) * 64 + lane) * 8);

    // --- convert Q -> fp16 (parallel, 2 per thread) ---
    Qh[(tid >> 5) * LDQ + (tid & 31)] = (half_t)Q[tid];
    Qh[((tid + 512) >> 5) * LDQ + (tid & 31)] = (half_t)Q[tid + 512];
    __syncthreads();

    // --- agg MFMA + m -> Am ---
#pragma unroll
    for (int mt = 0; mt < 2; ++mt) {
        f32x4 acc = {0.f, 0.f, 0.f, 0.f};
        f16x8 a = *(const f16x8*)&Qh[(mt * 16 + l16) * LDQ + quad * 8];
        acc = __builtin_amdgcn_mfma_f32_16x16x32_f16(a, aggB, acc, 0, 0, 0);
#pragma unroll
        for (int r = 0; r < 4; ++r) {
            float m = convAcc[mt][r] + cb + acc[r];
            Am[(mt * 16 + quad * 4 + r) * LDA + c] = (half_t)leaky(m);
        }
    }
    __syncthreads();

    // --- gi MFMAs + GRU combine ---
    f32x4 giA[2][3];
#pragma unroll
    for (int mt = 0; mt < 2; ++mt)
#pragma unroll
        for (int g = 0; g < 3; ++g) giA[mt][g] = f32x4{0.f, 0.f, 0.f, 0.f};
#pragma unroll
    for (int kt = 0; kt < 4; ++kt) {
        f16x8 a0 = *(const f16x8*)&Am[(0 + l16) * LDA + kt * 32 + quad * 8];
        f16x8 a1 = *(const f16x8*)&Am[(16 + l16) * LDA + kt * 32 + quad * 8];
#pragma unroll
        for (int g = 0; g < 3; ++g) {
            giA[0][g] = __builtin_amdgcn_mfma_f32_16x16x32_f16(a0, giB[g * 4 + kt], giA[0][g], 0, 0, 0);
            giA[1][g] = __builtin_amdgcn_mfma_f32_16x16x32_f16(a1, giB[g * 4 + kt], giA[1][g], 0, 0, 0);
        }
    }
#pragma unroll
    for (int mt = 0; mt < 2; ++mt) {
#pragma unroll
        for (int r = 0; r < 4; ++r) {
            int row = mt * 16 + quad * 4 + r;
            float rg = fast_sigmoid(giA[mt][0][r] + bi0 + ghA[mt][0][r] + bh0);
            float z = fast_sigmoid(giA[mt][1][r] + bi1 + ghA[mt][1][r] + bh1);
            float nn = fast_tanh(giA[mt][2][r] + bi2 + rg * (ghA[mt][2][r] + bh2));
            float hnew = (1.f - z) * nn + z * Hs[row * LDH + c];
            hF[(size_t)(n0 + row) * D + c] = hnew;
            As[row * LDA + c] = (half_t)hnew;
        }
    }

    if (writeP) {
        __syncthreads();
        if (w < 4) {
            int mt = w >> 1, nt = w & 1;
            f32x4 acc = {0.f, 0.f, 0.f, 0.f};
#pragma unroll
            for (int kt = 0; kt < 4; ++kt) {
                f16x8 b = *(const f16x8*)(bondTP + (size_t)((nt * 4 + kt) * 64 + lane) * 8);
                f16x8 a = *(const f16x8*)&As[(mt * 16 + l16) * LDA + kt * 32 + quad * 8];
                acc = __builtin_amdgcn_mfma_f32_16x16x32_f16(a, b, acc, 0, 0, 0);
            }
#pragma unroll
            for (int r = 0; r < 4; ++r)
                Pnext[(size_t)(n0 + mt * 16 + quad * 4 + r) * 32 + nt * 16 + l16] = acc[r];
        }
    }
}

// ---------------- stem head (MFMA) + fused gpred ----------------
__device__ __forceinline__ int lower_bound_dev(const int* a, int n, int v) {
    int lo = 0, hi = n;
    while (lo < hi) {
        int m = (lo + hi) >> 1;
        if (a[m] < v) lo = m + 1;
        else hi = m;
    }
    return lo;
}

__global__ __launch_bounds__(512) void k_heads(
    const float* __restrict__ hF, const int* __restrict__ sni, const int* __restrict__ stypes,
    const float* __restrict__ embStem,
    const half_t* __restrict__ s1P, const float* __restrict__ b1,
    const half_t* __restrict__ s2P, const float* __restrict__ b2,
    const half_t* __restrict__ s3P, const float* __restrict__ b3,
    const int* __restrict__ batch,
    const float* __restrict__ g1T, const float* __restrict__ gb1,
    const float* __restrict__ gw2, const float* __restrict__ gb2,
    float* __restrict__ dout) {
    __shared__ __align__(16) half_t cat[16 * LDA2];
    __shared__ __align__(16) half_t t1[16 * LDA];
    __shared__ __align__(16) half_t t2[16 * LDA];
    const int tid = threadIdx.x;
    if (blockIdx.x >= 256) {
        int g = blockIdx.x - 256;
        if (tid >= 128) return;
        __shared__ float mean_s[D];
        __shared__ float red[D];
        int j = tid;
        int lo = lower_bound_dev(batch, NNODES, g);
        int hi = lower_bound_dev(batch, NNODES, g + 1);
        float sum = 0.f;
        for (int n = lo; n < hi; ++n) sum += hF[(size_t)n * D + j];
        float denom = (hi > lo) ? (float)(hi - lo) : 1.0f;
        mean_s[j] = sum / denom;
        __syncthreads();
        float a = gb1[j];
        for (int i = 0; i < D; ++i) a += mean_s[i] * g1T[i * D + j];
        a = leaky(a);
        red[j] = a * gw2[j];
        __syncthreads();
        for (int off = 64; off > 0; off >>= 1) {
            if (j < off) red[j] += red[j + off];
            __syncthreads();
        }
        if (j == 0) dout[NSTEMS * OPS + g] = red[0] + gb2[0];
        return;
    }
    const int w = tid >> 6;
    const int lane = tid & 63;
    const int quad = lane >> 4;
    const int l16 = lane & 15;
    const int s0 = blockIdx.x * 16;
    const int c = w * 16 + l16;

    {
        int row = tid >> 5;
        int col = (tid & 31) * 8;
        const float* src;
        if (col < D) src = hF + (size_t)sni[s0 + row] * D + col;
        else src = embStem + (size_t)stypes[s0 + row] * D + (col - D);
        float4 v0 = ((const float4*)src)[0];
        float4 v1 = ((const float4*)src)[1];
        f16x8 hv;
        hv[0] = (half_t)v0.x; hv[1] = (half_t)v0.y; hv[2] = (half_t)v0.z; hv[3] = (half_t)v0.w;
        hv[4] = (half_t)v1.x; hv[5] = (half_t)v1.y; hv[6] = (half_t)v1.z; hv[7] = (half_t)v1.w;
        *(f16x8*)&cat[row * LDA2 + col] = hv;
    }
    __syncthreads();

    {
        f32x4 acc = {0.f, 0.f, 0.f, 0.f};
#pragma unroll
        for (int kt = 0; kt < 8; ++kt) {
            f16x8 b = *(const f16x8*)(s1P + (size_t)((w * 8 + kt) * 64 + lane) * 8);
            f16x8 a = *(const f16x8*)&cat[l16 * LDA2 + kt * 32 + quad * 8];
            acc = __builtin_amdgcn_mfma_f32_16x16x32_f16(a, b, acc, 0, 0, 0);
        }
        float bb = b1[c];
#pragma unroll
        for (int r = 0; r < 4; ++r)
            t1[(quad * 4 + r) * LDA + c] = (half_t)leaky(acc[r] + bb);
    }
    __syncthreads();
    {
        f32x4 acc = {0.f, 0.f, 0.f, 0.f};
#pragma unroll
        for (int kt = 0; kt < 4; ++kt) {
            f16x8 b = *(const f16x8*)(s2P + (size_t)((w * 4 + kt) * 64 + lane) * 8);
            f16x8 a = *(const f16x8*)&t1[l16 * LDA + kt * 32 + quad * 8];
            acc = __builtin_amdgcn_mfma_f32_16x16x32_f16(a, b, acc, 0, 0, 0);
        }
        float bb = b2[c];
#pragma unroll
        for (int r = 0; r < 4; ++r)
            t2[(quad * 4 + r) * LDA + c] = (half_t)leaky(acc[r] + bb);
    }
    __syncthreads();
    if (w < 7) {
        f32x4 acc = {0.f, 0.f, 0.f, 0.f};
#pragma unroll
        for (int kt = 0; kt < 4; ++kt) {
            f16x8 b = *(const f16x8*)(s3P + (size_t)((w * 4 + kt) * 64 + lane) * 8);
            f16x8 a = *(const f16x8*)&t2[l16 * LDA + kt * 32 + quad * 8];
            acc = __builtin_amdgcn_mfma_f32_16x16x32_f16(a, b, acc, 0, 0, 0);
        }
        int j = w * 16 + l16;
        if (j < OPS) {
            float bb = b3[j];
#pragma unroll
            for (int r = 0; r < 4; ++r)
                dout[(size_t)(s0 + quad * 4 + r) * OPS + j] = acc[r] + bb;
        }
    }
}

// ---------------- launch ----------------
extern "C" void kernel_launch(void* const* d_in, const int* in_sizes, int n_in,
                              void* d_out, int out_size, void* d_ws, size_t ws_size,
                              hipStream_t stream) {
    const int* x = (const int*)d_in[0];
    const int* stypes = (const int*)d_in[1];
    const int* eattr = (const int*)d_in[2];
    const int* eidx = (const int*)d_in[3];
    const int* sni = (const int*)d_in[4];
    const int* batch = (const int*)d_in[5];
    const float* embBlock = (const float*)d_in[6];
    const float* embStem = (const float*)d_in[7];
    const float* embBond = (const float*)d_in[8];
    const float* b2e_w1 = (const float*)d_in[9];
    const float* b2e_b1 = (const float*)d_in[10];
    const float* b2e_w2 = (const float*)d_in[11];
    const float* b2e_b2 = (const float*)d_in[12];
    const float* conv_root = (const float*)d_in[13];
    const float* conv_bias = (const float*)d_in[14];
    const float* gru_w_ih = (const float*)d_in[15];
    const float* gru_w_hh = (const float*)d_in[16];
    const float* gru_b_ih = (const float*)d_in[17];
    const float* gru_b_hh = (const float*)d_in[18];
    const float* s2p_w1 = (const float*)d_in[19];
    const float* s2p_b1 = (const float*)d_in[20];
    const float* s2p_w2 = (const float*)d_in[21];
    const float* s2p_b2 = (const float*)d_in[22];
    const float* s2p_w3 = (const float*)d_in[23];
    const float* s2p_b3 = (const float*)d_in[24];
    const float* g2p_w1 = (const float*)d_in[25];
    const float* g2p_b1 = (const float*)d_in[26];
    const float* g2p_w2 = (const float*)d_in[27];
    const float* g2p_b2 = (const float*)d_in[28];
    float* out_f = (float*)d_out;

    float* W = (float*)d_ws;
    size_t off = 0;
    auto alloc = [&](size_t words) {
        size_t o = off;
        off += (words + 3) & ~(size_t)3;
        return o;
    };
    float* hF = W + alloc(NNODES * D);
    float* P0 = W + alloc(NNODES * 32);
    float* P1 = W + alloc(NNODES * 32);
    half_t* rootP = (half_t*)(W + alloc(16384 / 2));
    half_t* WihP = (half_t*)(W + alloc(49152 / 2));
    half_t* WhhP = (half_t*)(W + alloc(49152 / 2));
    half_t* bondTP = (half_t*)(W + alloc(4096 / 2));
    half_t* s1P = (half_t*)(W + alloc(32768 / 2));
    half_t* s2P = (half_t*)(W + alloc(16384 / 2));
    half_t* s3P = (half_t*)(W + alloc(14336 / 2));
    half_t* w1P = (half_t*)(W + alloc(16384 / 2));
    half_t* w2P = (half_t*)(W + alloc(16384 / 2));
    half_t* bondQP = (half_t*)(W + alloc(4096 / 2));
    float* g1T = W + alloc(128 * 128);
    int* row_start = (int*)(W + alloc(NNODES + 1));
    int4* epack = (int4*)(W + alloc(NEDGES * 4));
    float* inv_deg = W + alloc(NNODES);
    float* zbase = W + alloc(2 * NNODES);   // deg + fill
    int* deg = (int*)zbase;
    int* fill = deg + NNODES;

    k_setup<<<dim3(192, 12), 256, 0, stream>>>(
        conv_root, gru_w_ih, gru_w_hh, embBond, s2p_w1, s2p_w2, s2p_w3,
        b2e_w1, b2e_w2, g2p_w1,
        rootP, WihP, WhhP, bondTP, s1P, s2P, s3P, w1P, w2P, bondQP,
        g1T, (int*)zbase);
    k_deg<<<(NEDGES + 255) / 256, 256, 0, stream>>>(eidx, deg);
    k_scan<<<1, 256, 0, stream>>>(deg, row_start, inv_deg);
    k_scatter<<<(NEDGES + 255) / 256, 256, 0, stream>>>(eidx, eattr, row_start, fill, epack);
    k_init<<<NNODES / MT, 512, 0, stream>>>(x, embBlock, w1P, b2e_b1, w2P, b2e_b2,
                                            bondTP, hF, P0);

    for (int step = 0; step < NSTEPS; ++step) {
        const float* Pprev = (step & 1) ? P1 : P0;
        float* Pnext = (step & 1) ? P0 : P1;
        int writeP = (step < NSTEPS - 1) ? 1 : 0;
        k_step<<<NB, 512, 0, stream>>>(
            hF, Pprev, Pnext, rootP, WihP, WhhP, bondTP, bondQP,
            conv_bias, gru_b_ih, gru_b_hh,
            epack, row_start, inv_deg, writeP);
    }

    k_heads<<<NSTEMS / 16 + NGRAPHS, 512, 0, stream>>>(
        hF, sni, stypes, embStem,
        s1P, s2p_b1, s2P, s2p_b2, s3P, s2p_b3,
        batch, g1T, g2p_b1, g2p_w2, g2p_b2, out_f);
}